// Round 10
// baseline (1100.518 us; speedup 1.0000x reference)
//
#include <hip/hip_runtime.h>
#include <hip/hip_bf16.h>
#include <math.h>

typedef __hip_bfloat16 bf16;
typedef __attribute__((ext_vector_type(8))) short short8;
typedef __attribute__((ext_vector_type(8))) unsigned short ushort8;
typedef __attribute__((ext_vector_type(4))) float f32x4;

#define NT_   2048
#define NTOK_ 4096
#define DM_   1024
#define DHID_ 4096
#define NEXP_ 8

__device__ __forceinline__ unsigned short f2bf(float f) {
    unsigned u = __float_as_uint(f);
    u = u + 0x7FFF + ((u >> 16) & 1);
    return (unsigned short)(u >> 16);
}

// ============================ fp32 -> bf16 convert (flat) ==========================
__global__ __launch_bounds__(256) void c2b(const float* __restrict__ in,
        unsigned short* __restrict__ out, int n8)
{
    int i = blockIdx.x * 256 + threadIdx.x;
    if (i >= n8) return;
    const float4 v0 = *(const float4*)(in + (size_t)i * 8);
    const float4 v1 = *(const float4*)(in + (size_t)i * 8 + 4);
    ushort8 o;
    o[0] = f2bf(v0.x); o[1] = f2bf(v0.y); o[2] = f2bf(v0.z); o[3] = f2bf(v0.w);
    o[4] = f2bf(v1.x); o[5] = f2bf(v1.y); o[6] = f2bf(v1.z); o[7] = f2bf(v1.w);
    *(ushort8*)(out + (size_t)i * 8) = o;
}

// ================== transpose+convert: in f32 [R][C] -> out bf16 [C][R] ============
__global__ __launch_bounds__(256) void tconv(const float* __restrict__ in,
        unsigned short* __restrict__ out, int R, int C)
{
    __shared__ float t[64][65];
    const size_t mofs = (size_t)blockIdx.z * R * C;
    const int r0 = blockIdx.y * 64, c0 = blockIdx.x * 64;
    const int tid = threadIdx.x;
    const int lr = tid >> 4, lc4 = (tid & 15) * 4;
    #pragma unroll
    for (int i = 0; i < 4; ++i) {
        float4 v = *(const float4*)(in + mofs + (size_t)(r0 + lr + i * 16) * C + c0 + lc4);
        t[lr + i * 16][lc4 + 0] = v.x; t[lr + i * 16][lc4 + 1] = v.y;
        t[lr + i * 16][lc4 + 2] = v.z; t[lr + i * 16][lc4 + 3] = v.w;
    }
    __syncthreads();
    const int oc = tid >> 2;
    const int j0 = (tid & 3) * 16;
    ushort8 o0, o1;
    #pragma unroll
    for (int j = 0; j < 8; ++j)  o0[j] = f2bf(t[j0 + j][oc]);
    #pragma unroll
    for (int j = 0; j < 8; ++j)  o1[j] = f2bf(t[j0 + 8 + j][oc]);
    size_t ob = mofs + (size_t)(c0 + oc) * R + r0 + j0;
    *(ushort8*)(out + ob) = o0;
    *(ushort8*)(out + ob + 8) = o1;
}

// three separate sources (batched over z), same R=C=1024
__global__ __launch_bounds__(256) void tconv3(const float* __restrict__ s0,
        const float* __restrict__ s1, const float* __restrict__ s2,
        unsigned short* __restrict__ out)
{
    __shared__ float t[64][65];
    const float* in = blockIdx.z == 0 ? s0 : (blockIdx.z == 1 ? s1 : s2);
    unsigned short* o = out + (size_t)blockIdx.z * DM_ * DM_;
    const int r0 = blockIdx.y * 64, c0 = blockIdx.x * 64;
    const int tid = threadIdx.x;
    const int lr = tid >> 4, lc4 = (tid & 15) * 4;
    #pragma unroll
    for (int i = 0; i < 4; ++i) {
        float4 v = *(const float4*)(in + (size_t)(r0 + lr + i * 16) * DM_ + c0 + lc4);
        t[lr + i * 16][lc4 + 0] = v.x; t[lr + i * 16][lc4 + 1] = v.y;
        t[lr + i * 16][lc4 + 2] = v.z; t[lr + i * 16][lc4 + 3] = v.w;
    }
    __syncthreads();
    const int oc = tid >> 2;
    const int j0 = (tid & 3) * 16;
    ushort8 o0, o1;
    #pragma unroll
    for (int j = 0; j < 8; ++j)  o0[j] = f2bf(t[j0 + j][oc]);
    #pragma unroll
    for (int j = 0; j < 8; ++j)  o1[j] = f2bf(t[j0 + 8 + j][oc]);
    size_t ob = (size_t)(c0 + oc) * DM_ + r0 + j0;
    *(ushort8*)(o + ob) = o0;
    *(ushort8*)(o + ob + 8) = o1;
}

// =========== MFMA GEMM: C f32[M,N] = A bf16[M,K] @ (BT bf16[N,K])^T ================
__global__ __launch_bounds__(256) void gemm_bf16_128(
        const unsigned short* __restrict__ A, const unsigned short* __restrict__ BT,
        float* __restrict__ C, int M, int N, int K)
{
    __shared__ unsigned short As[128 * 64];
    __shared__ unsigned short Bs[128 * 64];
    const int tid = threadIdx.x;
    const int wid = tid >> 6, lane = tid & 63;
    const int m0 = blockIdx.y * 128, n0 = blockIdx.x * 128;

    const unsigned short* aSrc[4]; const unsigned short* bSrc[4]; int sWr[4];
    #pragma unroll
    for (int i = 0; i < 4; ++i) {
        int idx = tid + 256 * i;
        int row = idx >> 3, c8 = idx & 7;
        int ar = m0 + row; if (ar >= M) ar = M - 1;
        aSrc[i] = A + (size_t)ar * K + c8 * 8;
        bSrc[i] = BT + (size_t)(n0 + row) * K + c8 * 8;
        sWr[i] = (row * 128 + c8 * 16) ^ ((row & 7) << 4);
    }
    const int wr = wid >> 1, wc = wid & 1;
    int ra[2][4], rb[2][4];
    #pragma unroll
    for (int kk = 0; kk < 2; ++kk) {
        #pragma unroll
        for (int t = 0; t < 4; ++t) {
            int kb = kk * 64 + (lane >> 4) * 16;
            int rowa = wr * 64 + t * 16 + (lane & 15);
            ra[kk][t] = (rowa * 128 + kb) ^ ((rowa & 7) << 4);
            int rowb = wc * 64 + t * 16 + (lane & 15);
            rb[kk][t] = (rowb * 128 + kb) ^ ((rowb & 7) << 4);
        }
    }
    const f32x4 zero = {0.f, 0.f, 0.f, 0.f};
    f32x4 acc[4][4];
    #pragma unroll
    for (int i = 0; i < 4; ++i)
        #pragma unroll
        for (int j = 0; j < 4; ++j) acc[i][j] = zero;

    short8 sa[4], sb[4];
    #pragma unroll
    for (int i = 0; i < 4; ++i) { sa[i] = *(const short8*)(aSrc[i]); sb[i] = *(const short8*)(bSrc[i]); }
    const int nk = K >> 6;
    for (int kt = 0; kt < nk; ++kt) {
        #pragma unroll
        for (int i = 0; i < 4; ++i) {
            *(short8*)((char*)As + sWr[i]) = sa[i];
            *(short8*)((char*)Bs + sWr[i]) = sb[i];
        }
        __syncthreads();
        if (kt + 1 < nk) {
            int ko = (kt + 1) << 6;
            #pragma unroll
            for (int i = 0; i < 4; ++i) { sa[i] = *(const short8*)(aSrc[i] + ko); sb[i] = *(const short8*)(bSrc[i] + ko); }
        }
        #pragma unroll
        for (int kk = 0; kk < 2; ++kk) {
            short8 af[4], bfr[4];
            #pragma unroll
            for (int t = 0; t < 4; ++t) {
                af[t]  = *(const short8*)((const char*)As + ra[kk][t]);
                bfr[t] = *(const short8*)((const char*)Bs + rb[kk][t]);
            }
            #pragma unroll
            for (int i = 0; i < 4; ++i)
                #pragma unroll
                for (int j = 0; j < 4; ++j)
                    acc[i][j] = __builtin_amdgcn_mfma_f32_16x16x32_bf16(af[i], bfr[j], acc[i][j], 0, 0, 0);
        }
        __syncthreads();
    }
    const int cl = lane & 15, g4 = lane >> 4;
    #pragma unroll
    for (int i = 0; i < 4; ++i)
        #pragma unroll
        for (int j = 0; j < 4; ++j)
            #pragma unroll
            for (int r = 0; r < 4; ++r) {
                int rr = m0 + wr * 64 + i * 16 + g4 * 4 + r;
                if (rr < M) C[(size_t)rr * N + n0 + wc * 64 + j * 16 + cl] = acc[i][j][r];
            }
}

// ====== batched projections x@{Wk,Wv,Wq} with fused RoPE on z=0 (K) and z=2 (Q) ====
__global__ __launch_bounds__(256) void gemm_proj3(
        const unsigned short* __restrict__ A, const unsigned short* __restrict__ BT0,
        float* __restrict__ C0, const float* __restrict__ cosb,
        const float* __restrict__ sinb)
{
    const int z = blockIdx.z;
    const unsigned short* BT = BT0 + (size_t)z * DM_ * DM_;
    float* C = C0 + (size_t)z * NTOK_ * DM_;
    const bool doRope = (z != 1);
    __shared__ unsigned short As[128 * 64];
    __shared__ unsigned short Bs[128 * 64];
    const int tid = threadIdx.x;
    const int wid = tid >> 6, lane = tid & 63;
    const int m0 = blockIdx.y * 128, n0 = blockIdx.x * 128;
    const int K = DM_, N = DM_;

    const unsigned short* aSrc[4]; const unsigned short* bSrc[4]; int sWr[4];
    #pragma unroll
    for (int i = 0; i < 4; ++i) {
        int idx = tid + 256 * i;
        int row = idx >> 3, c8 = idx & 7;
        aSrc[i] = A + (size_t)(m0 + row) * K + c8 * 8;
        bSrc[i] = BT + (size_t)(n0 + row) * K + c8 * 8;
        sWr[i] = (row * 128 + c8 * 16) ^ ((row & 7) << 4);
    }
    const int wr = wid >> 1, wc = wid & 1;
    int ra[2][4], rb[2][4];
    #pragma unroll
    for (int kk = 0; kk < 2; ++kk) {
        #pragma unroll
        for (int t = 0; t < 4; ++t) {
            int kb = kk * 64 + (lane >> 4) * 16;
            int rowa = wr * 64 + t * 16 + (lane & 15);
            ra[kk][t] = (rowa * 128 + kb) ^ ((rowa & 7) << 4);
            int rowb = wc * 64 + t * 16 + (lane & 15);
            rb[kk][t] = (rowb * 128 + kb) ^ ((rowb & 7) << 4);
        }
    }
    const f32x4 zero = {0.f, 0.f, 0.f, 0.f};
    f32x4 acc[4][4];
    #pragma unroll
    for (int i = 0; i < 4; ++i)
        #pragma unroll
        for (int j = 0; j < 4; ++j) acc[i][j] = zero;

    short8 sa[4], sb[4];
    #pragma unroll
    for (int i = 0; i < 4; ++i) { sa[i] = *(const short8*)(aSrc[i]); sb[i] = *(const short8*)(bSrc[i]); }
    const int nk = K >> 6;
    for (int kt = 0; kt < nk; ++kt) {
        #pragma unroll
        for (int i = 0; i < 4; ++i) {
            *(short8*)((char*)As + sWr[i]) = sa[i];
            *(short8*)((char*)Bs + sWr[i]) = sb[i];
        }
        __syncthreads();
        if (kt + 1 < nk) {
            int ko = (kt + 1) << 6;
            #pragma unroll
            for (int i = 0; i < 4; ++i) { sa[i] = *(const short8*)(aSrc[i] + ko); sb[i] = *(const short8*)(bSrc[i] + ko); }
        }
        #pragma unroll
        for (int kk = 0; kk < 2; ++kk) {
            short8 af[4], bfr[4];
            #pragma unroll
            for (int t = 0; t < 4; ++t) {
                af[t]  = *(const short8*)((const char*)As + ra[kk][t]);
                bfr[t] = *(const short8*)((const char*)Bs + rb[kk][t]);
            }
            #pragma unroll
            for (int i = 0; i < 4; ++i)
                #pragma unroll
                for (int j = 0; j < 4; ++j)
                    acc[i][j] = __builtin_amdgcn_mfma_f32_16x16x32_bf16(af[i], bfr[j], acc[i][j], 0, 0, 0);
        }
        __syncthreads();
    }
    const int cl = lane & 15, g4 = lane >> 4;
    #pragma unroll
    for (int i = 0; i < 4; ++i)
        #pragma unroll
        for (int j = 0; j < 4; ++j) {
            const int cc = n0 + wc * 64 + j * 16 + cl;
            const int ii = (cc & 63) >> 1;
            const bool even = (cc & 1) == 0;
            #pragma unroll
            for (int r = 0; r < 4; ++r) {
                const int rr = m0 + wr * 64 + i * 16 + g4 * 4 + r;
                float v = acc[i][j][r];
                float p = __shfl_xor(v, 1, 64);
                float o = v;
                if (doRope) {
                    const int t = rr & (NT_ - 1);
                    float cv = cosb[t * 32 + ii], sv = sinb[t * 32 + ii];
                    o = even ? (v * cv - p * sv) : (p * sv + v * cv);
                }
                C[(size_t)rr * N + cc] = o;
            }
        }
}

// ====== small latent GEMM, batched: C[z] f32[M,1024] = A bf16[M,1024] @ BT[z]^T ====
__global__ __launch_bounds__(256) void gemm_lat(
        const unsigned short* __restrict__ A, const unsigned short* __restrict__ BT0,
        int btStride, float* __restrict__ C0, int cStride, int M)
{
    const int z = blockIdx.y;
    const unsigned short* BT = BT0 + (size_t)z * btStride;
    float* C = C0 + (size_t)z * cStride;
    const int n0 = blockIdx.x * 64;
    __shared__ unsigned short As[128 * 64];
    __shared__ unsigned short Bs[64 * 64];
    const int tid = threadIdx.x;
    const int wid = tid >> 6, lane = tid & 63;

    const unsigned short* aSrc[4]; int aWr[4];
    #pragma unroll
    for (int i = 0; i < 4; ++i) {
        int idx = tid + 256 * i;
        int row = idx >> 3, c8 = idx & 7;
        int ar = row; if (ar >= M) ar = M - 1;
        aSrc[i] = A + (size_t)ar * DM_ + c8 * 8;
        aWr[i] = (row * 128 + c8 * 16) ^ ((row & 7) << 4);
    }
    const unsigned short* bSrc[2]; int bWr[2];
    #pragma unroll
    for (int i = 0; i < 2; ++i) {
        int idx = tid + 256 * i;
        int row = idx >> 3, c8 = idx & 7;
        bSrc[i] = BT + (size_t)(n0 + row) * DM_ + c8 * 8;
        bWr[i] = (row * 128 + c8 * 16) ^ ((row & 7) << 4);
    }
    const int wr = wid >> 1, wc = wid & 1;
    int ra[2][4], rb[2][2];
    #pragma unroll
    for (int kk = 0; kk < 2; ++kk) {
        #pragma unroll
        for (int t = 0; t < 4; ++t) {
            int rowa = wr * 64 + t * 16 + (lane & 15);
            int kb = kk * 64 + (lane >> 4) * 16;
            ra[kk][t] = (rowa * 128 + kb) ^ ((rowa & 7) << 4);
        }
        #pragma unroll
        for (int t = 0; t < 2; ++t) {
            int rowb = wc * 32 + t * 16 + (lane & 15);
            int kb = kk * 64 + (lane >> 4) * 16;
            rb[kk][t] = (rowb * 128 + kb) ^ ((rowb & 7) << 4);
        }
    }
    const f32x4 zero = {0.f, 0.f, 0.f, 0.f};
    f32x4 acc[4][2];
    #pragma unroll
    for (int i = 0; i < 4; ++i)
        #pragma unroll
        for (int j = 0; j < 2; ++j) acc[i][j] = zero;

    short8 sa[4], sb[2];
    #pragma unroll
    for (int i = 0; i < 4; ++i) sa[i] = *(const short8*)(aSrc[i]);
    #pragma unroll
    for (int i = 0; i < 2; ++i) sb[i] = *(const short8*)(bSrc[i]);
    const int nk = DM_ >> 6;
    for (int kt = 0; kt < nk; ++kt) {
        #pragma unroll
        for (int i = 0; i < 4; ++i) *(short8*)((char*)As + aWr[i]) = sa[i];
        #pragma unroll
        for (int i = 0; i < 2; ++i) *(short8*)((char*)Bs + bWr[i]) = sb[i];
        __syncthreads();
        if (kt + 1 < nk) {
            int ko = (kt + 1) << 6;
            #pragma unroll
            for (int i = 0; i < 4; ++i) sa[i] = *(const short8*)(aSrc[i] + ko);
            #pragma unroll
            for (int i = 0; i < 2; ++i) sb[i] = *(const short8*)(bSrc[i] + ko);
        }
        #pragma unroll
        for (int kk = 0; kk < 2; ++kk) {
            short8 af[4], bf2[2];
            #pragma unroll
            for (int t = 0; t < 4; ++t) af[t] = *(const short8*)((const char*)As + ra[kk][t]);
            #pragma unroll
            for (int t = 0; t < 2; ++t) bf2[t] = *(const short8*)((const char*)Bs + rb[kk][t]);
            #pragma unroll
            for (int i = 0; i < 4; ++i)
                #pragma unroll
                for (int j = 0; j < 2; ++j)
                    acc[i][j] = __builtin_amdgcn_mfma_f32_16x16x32_bf16(af[i], bf2[j], acc[i][j], 0, 0, 0);
        }
        __syncthreads();
    }
    const int cl = lane & 15, g4 = lane >> 4;
    #pragma unroll
    for (int i = 0; i < 4; ++i)
        #pragma unroll
        for (int j = 0; j < 2; ++j)
            #pragma unroll
            for (int r = 0; r < 4; ++r) {
                int rl = wr * 64 + i * 16 + g4 * 4 + r;
                if (rl < M)
                    C[(size_t)rl * DM_ + n0 + wc * 32 + j * 16 + cl] = acc[i][j][r];
            }
}

// ---------------- attention scores (attn1 only) -------------------------------------
__global__ __launch_bounds__(256) void attn_scores(float* __restrict__ S,
        const float* __restrict__ Q, const float* __restrict__ Km,
        int M, int T, int q_bs, int k_bs, float scale)
{
    const int bh = blockIdx.z, b = bh >> 4, h = bh & 15;
    const int t0 = blockIdx.x * 64, q0 = blockIdx.y * 64;
    __shared__ float Qs[64][65], Ks[64][65];
    const int tid = threadIdx.x;
    const int lr = tid >> 2, lc = (tid & 3) * 16;
    {
        int q = q0 + lr;
        if (q < M) {
            const float* Qp = Q + ((size_t)q_bs * b + q) * DM_ + h * 64 + lc;
            #pragma unroll
            for (int j = 0; j < 16; ++j) Qs[lr][lc + j] = Qp[j];
        } else {
            #pragma unroll
            for (int j = 0; j < 16; ++j) Qs[lr][lc + j] = 0.f;
        }
        const float* Kp = Km + ((size_t)k_bs * b + t0 + lr) * DM_ + h * 64 + lc;
        #pragma unroll
        for (int j = 0; j < 16; ++j) Ks[lr][lc + j] = Kp[j];
    }
    __syncthreads();
    const int ty = tid >> 4, tx = tid & 15;
    float acc[4][4] = {};
    for (int d = 0; d < 64; ++d) {
        float a[4], kk[4];
        #pragma unroll
        for (int i = 0; i < 4; ++i) a[i] = Qs[ty * 4 + i][d];
        #pragma unroll
        for (int j = 0; j < 4; ++j) kk[j] = Ks[tx * 4 + j][d];
        #pragma unroll
        for (int i = 0; i < 4; ++i)
            #pragma unroll
            for (int j = 0; j < 4; ++j) acc[i][j] += a[i] * kk[j];
    }
    #pragma unroll
    for (int i = 0; i < 4; ++i) {
        int q = q0 + ty * 4 + i;
        if (q < M) {
            float* Sp = S + ((size_t)bh * M + q) * T + t0 + tx * 4;
            #pragma unroll
            for (int j = 0; j < 4; ++j) Sp[j] = acc[i][j] * scale;
        }
    }
}

// ---------------- row softmax (attn1, L=2048) ---------------------------------------
__global__ __launch_bounds__(256) void softmax_rows(float* __restrict__ S, int L)
{
    float* p = S + (size_t)blockIdx.x * L;
    const int tid = threadIdx.x;
    __shared__ float red[256];
    float m = -1e30f;
    for (int i = tid; i < L; i += 256) m = fmaxf(m, p[i]);
    red[tid] = m; __syncthreads();
    for (int s = 128; s; s >>= 1) { if (tid < s) red[tid] = fmaxf(red[tid], red[tid + s]); __syncthreads(); }
    m = red[0]; __syncthreads();
    float sum = 0.f;
    for (int i = tid; i < L; i += 256) { float e = __expf(p[i] - m); p[i] = e; sum += e; }
    red[tid] = sum; __syncthreads();
    for (int s = 128; s; s >>= 1) { if (tid < s) red[tid] += red[tid + s]; __syncthreads(); }
    float inv = 1.f / red[0];
    for (int i = tid; i < L; i += 256) p[i] *= inv;
}

// ====== fused attention for T=64 (attn2/attn3): QK^T -> softmax -> PV -> bf16 ======
__global__ __launch_bounds__(256) void fused_attn64(unsigned short* __restrict__ Ob,
        const float* __restrict__ Q, const float* __restrict__ Kp,
        const float* __restrict__ Vp, int q_bs)
{
    const int bh = blockIdx.y, b = bh >> 4, h = bh & 15;
    const int q0 = blockIdx.x * 64;
    __shared__ float Qs[64][65], Ks[64][65], Vs[64][65];
    __shared__ float ls[64];
    const int tid = threadIdx.x;
    const int lr = tid >> 2, lc = (tid & 3) * 16;
    {
        const float* Qr = Q + ((size_t)q_bs * b + q0 + lr) * DM_ + h * 64 + lc;
        #pragma unroll
        for (int j = 0; j < 16; ++j) Qs[lr][lc + j] = Qr[j];
        const float* Kr = Kp + ((size_t)64 * b + lr) * DM_ + h * 64 + lc;
        #pragma unroll
        for (int j = 0; j < 16; ++j) Ks[lr][lc + j] = Kr[j];
        const float* Vr = Vp + ((size_t)64 * b + lr) * DM_ + h * 64 + lc;
        #pragma unroll
        for (int j = 0; j < 16; ++j) Vs[lr][lc + j] = Vr[j];
    }
    __syncthreads();
    const int ty = tid >> 4, tx = tid & 15;
    float acc[4][4] = {};
    for (int d = 0; d < 64; ++d) {
        float a[4], kk[4];
        #pragma unroll
        for (int i = 0; i < 4; ++i) a[i] = Qs[ty * 4 + i][d];
        #pragma unroll
        for (int j = 0; j < 4; ++j) kk[j] = Ks[tx * 4 + j][d];
        #pragma unroll
        for (int i = 0; i < 4; ++i)
            #pragma unroll
            for (int j = 0; j < 4; ++j) acc[i][j] += a[i] * kk[j];
    }
    float p[4][4]; float lsum[4];
    #pragma unroll
    for (int i = 0; i < 4; ++i) {
        float m = fmaxf(fmaxf(acc[i][0], acc[i][1]), fmaxf(acc[i][2], acc[i][3]));
        #pragma unroll
        for (int o = 1; o <= 8; o <<= 1) m = fmaxf(m, __shfl_xor(m, o, 64));
        float s = 0.f;
        #pragma unroll
        for (int j = 0; j < 4; ++j) { p[i][j] = __expf(acc[i][j] * 0.125f - m * 0.125f); s += p[i][j]; }
        #pragma unroll
        for (int o = 1; o <= 8; o <<= 1) s += __shfl_xor(s, o, 64);
        lsum[i] = s;
    }
    __syncthreads();
    #pragma unroll
    for (int i = 0; i < 4; ++i) {
        #pragma unroll
        for (int j = 0; j < 4; ++j) Qs[ty * 4 + i][tx * 4 + j] = p[i][j];
        if (tx == 0) ls[ty * 4 + i] = lsum[i];
    }
    __syncthreads();
    float O[4][4] = {};
    for (int t = 0; t < 64; ++t) {
        float pp[4], vv[4];
        #pragma unroll
        for (int i = 0; i < 4; ++i) pp[i] = Qs[ty * 4 + i][t];
        #pragma unroll
        for (int j = 0; j < 4; ++j) vv[j] = Vs[t][tx * 4 + j];
        #pragma unroll
        for (int i = 0; i < 4; ++i)
            #pragma unroll
            for (int j = 0; j < 4; ++j) O[i][j] += pp[i] * vv[j];
    }
    #pragma unroll
    for (int i = 0; i < 4; ++i) {
        float inv = 1.f / ls[ty * 4 + i];
        size_t ofs = ((size_t)q_bs * b + q0 + ty * 4 + i) * DM_ + h * 64 + tx * 4;
        #pragma unroll
        for (int j = 0; j < 4; ++j) Ob[ofs + j] = f2bf(O[i][j] * inv);
    }
}

// ---------------- attn1 PV split over T: partial[bh][c][64q][64d] -------------------
__global__ __launch_bounds__(256) void pv_split(float* __restrict__ part,
        const float* __restrict__ P, const float* __restrict__ V)
{
    const int c = blockIdx.x, bh = blockIdx.y, b = bh >> 4, h = bh & 15;
    __shared__ float Ps[64][65], Vs[64][65];
    const int tid = threadIdx.x;
    const int lr = tid >> 2, lc = (tid & 3) * 16;
    const int ty = tid >> 4, tx = tid & 15;
    float acc[4][4] = {};
    for (int it = 0; it < 4; ++it) {
        const int t0 = c * 256 + it * 64;
        const float* Pp = P + ((size_t)bh * 64 + lr) * NT_ + t0 + lc;
        #pragma unroll
        for (int j = 0; j < 16; ++j) Ps[lr][lc + j] = Pp[j];
        const float* Vp = V + ((size_t)NT_ * b + t0 + lr) * DM_ + h * 64 + lc;
        #pragma unroll
        for (int j = 0; j < 16; ++j) Vs[lr][lc + j] = Vp[j];
        __syncthreads();
        for (int t = 0; t < 64; ++t) {
            float pp[4], vv[4];
            #pragma unroll
            for (int i = 0; i < 4; ++i) pp[i] = Ps[ty * 4 + i][t];
            #pragma unroll
            for (int j = 0; j < 4; ++j) vv[j] = Vs[t][tx * 4 + j];
            #pragma unroll
            for (int i = 0; i < 4; ++i)
                #pragma unroll
                for (int j = 0; j < 4; ++j) acc[i][j] += pp[i] * vv[j];
        }
        __syncthreads();
    }
    float* op = part + ((size_t)bh * 8 + c) * 4096;
    #pragma unroll
    for (int i = 0; i < 4; ++i)
        #pragma unroll
        for (int j = 0; j < 4; ++j)
            op[(ty * 4 + i) * 64 + tx * 4 + j] = acc[i][j];
}

__global__ __launch_bounds__(256) void pv_combine(const float* __restrict__ part,
        unsigned short* __restrict__ Zb)
{
    const int bh = blockIdx.x, b = bh >> 4, h = bh & 15;
    for (int idx = threadIdx.x; idx < 4096; idx += 256) {
        int q = idx >> 6, d = idx & 63;
        float s = 0.f;
        #pragma unroll
        for (int c = 0; c < 8; ++c) s += part[((size_t)bh * 8 + c) * 4096 + idx];
        Zb[(size_t)(b * 64 + q) * DM_ + h * 64 + d] = f2bf(s);
    }
}

// ---------------- LayerNorm + add, fp32 + bf16 outputs ------------------------------
__global__ __launch_bounds__(256) void ln_add_dual(const float* __restrict__ X,
        const float* __restrict__ g, const float* __restrict__ bb,
        const float* __restrict__ add, float* __restrict__ out,
        unsigned short* __restrict__ outb)
{
    const int n = blockIdx.x, tid = threadIdx.x;
    const float* x = X + (size_t)n * DM_;
    __shared__ float red[256];
    float v[4]; float s = 0.f;
    #pragma unroll
    for (int i = 0; i < 4; ++i) { v[i] = x[tid + i * 256]; s += v[i]; }
    red[tid] = s; __syncthreads();
    for (int st = 128; st; st >>= 1) { if (tid < st) red[tid] += red[tid + st]; __syncthreads(); }
    float mean = red[0] * (1.f / 1024.f);
    __syncthreads();
    float vs = 0.f;
    #pragma unroll
    for (int i = 0; i < 4; ++i) { float d = v[i] - mean; vs += d * d; }
    red[tid] = vs; __syncthreads();
    for (int st = 128; st; st >>= 1) { if (tid < st) red[tid] += red[tid + st]; __syncthreads(); }
    float inv = 1.f / (sqrtf(red[0] * (1.f / 1023.f)) + 1e-6f);
    #pragma unroll
    for (int i = 0; i < 4; ++i) {
        int d = tid + i * 256;
        float r = g[d] * (v[i] - mean) * inv + bb[d] + add[(size_t)n * DM_ + d];
        out[(size_t)n * DM_ + d] = r;
        outb[(size_t)n * DM_ + d] = f2bf(r);
    }
}

// ---------------- final LN ----------------------------------------------------------
__global__ __launch_bounds__(256) void ln_final(const float* __restrict__ X,
        const float* __restrict__ g, const float* __restrict__ bb,
        const float* __restrict__ t, const float* __restrict__ lb,
        float* __restrict__ out)
{
    const int n = blockIdx.x, tid = threadIdx.x;
    const float* x = X + (size_t)n * DM_;
    __shared__ float red[256];
    float v[4]; float s = 0.f;
    #pragma unroll
    for (int i = 0; i < 4; ++i) { v[i] = x[tid + i * 256]; s += v[i]; }
    red[tid] = s; __syncthreads();
    for (int st = 128; st; st >>= 1) { if (tid < st) red[tid] += red[tid + st]; __syncthreads(); }
    float mean = red[0] * (1.f / 1024.f);
    __syncthreads();
    float vs = 0.f;
    #pragma unroll
    for (int i = 0; i < 4; ++i) { float d = v[i] - mean; vs += d * d; }
    red[tid] = vs; __syncthreads();
    for (int st = 128; st; st >>= 1) { if (tid < st) red[tid] += red[tid + st]; __syncthreads(); }
    float inv = 1.f / (sqrtf(red[0] * (1.f / 1023.f)) + 1e-6f);
    #pragma unroll
    for (int i = 0; i < 4; ++i) {
        int d = tid + i * 256;
        out[(size_t)n * DM_ + d] = g[d] * (v[i] - mean) * inv + bb[d]
                                 + t[(size_t)n * DM_ + d] + lb[d];
    }
}

// ---------------- router ------------------------------------------------------------
__global__ __launch_bounds__(256) void router_kernel(const float* __restrict__ X1,
        const float* __restrict__ Wr, const float* __restrict__ br,
        int* __restrict__ topi, float* __restrict__ gates, int* __restrict__ counts)
{
    const int n = blockIdx.x, tid = threadIdx.x;
    const int e = tid >> 5, l = tid & 31;
    const float* x = X1 + (size_t)n * DM_;
    float s = 0.f;
    for (int k = l; k < DM_; k += 32) s += x[k] * Wr[k * NEXP_ + e];
    for (int off = 16; off; off >>= 1) s += __shfl_down(s, off, 32);
    __shared__ float lg[NEXP_];
    if (l == 0) lg[e] = s + br[e];
    __syncthreads();
    if (tid == 0) {
        float v1 = -1e30f; int i1 = 0;
        for (int ee = 0; ee < NEXP_; ++ee) if (lg[ee] > v1) { v1 = lg[ee]; i1 = ee; }
        float v2 = -1e30f; int i2 = 0;
        for (int ee = 0; ee < NEXP_; ++ee) if (ee != i1 && lg[ee] > v2) { v2 = lg[ee]; i2 = ee; }
        float e2 = __expf(v2 - v1);
        float inv = 1.f / (1.f + e2);
        topi[n * 2] = i1; topi[n * 2 + 1] = i2;
        gates[n * 2] = inv; gates[n * 2 + 1] = e2 * inv;
        atomicAdd(&counts[i1], 1); atomicAdd(&counts[i2], 1);
    }
}

__global__ void zero_counts(int* __restrict__ counts)
{
    if (threadIdx.x < NEXP_) counts[threadIdx.x] = 0;
}

__global__ void router_offsets(const int* __restrict__ counts, int* __restrict__ offs,
                               int* __restrict__ fill)
{
    if (threadIdx.x == 0) {
        int acc = 0;
        for (int e = 0; e < NEXP_; ++e) { offs[e] = acc; acc += counts[e]; fill[e] = 0; }
    }
}

__global__ __launch_bounds__(256) void router_scatter(const int* __restrict__ topi,
        int* __restrict__ fill, const int* __restrict__ offs,
        int* __restrict__ ptok, int* __restrict__ pidx)
{
    int n = blockIdx.x * 256 + threadIdx.x;
    if (n >= NTOK_) return;
    #pragma unroll
    for (int s2 = 0; s2 < 2; ++s2) {
        int e = topi[n * 2 + s2];
        int r = atomicAdd(&fill[e], 1);
        int p = offs[e] + r;
        ptok[p] = n;
        pidx[n * 2 + s2] = p;
    }
}

// ====== MoE up: 128x64 dual tile; A via LDS, W/V fragments DIRECT from global ======
__global__ __launch_bounds__(256) void moe_up_mfma(
        const unsigned short* __restrict__ X1b,
        const unsigned short* __restrict__ WTa, const unsigned short* __restrict__ VTa,
        unsigned short* __restrict__ H,
        const int* __restrict__ cnt, const int* __restrict__ offs,
        const int* __restrict__ ptok)
{
    const int e = blockIdx.z;
    const int ce = cnt[e];
    const int m0 = blockIdx.y * 128;
    if (m0 >= ce) return;
    const int n0 = blockIdx.x * 64;
    const int base = offs[e];
    const unsigned short* WT = WTa + (size_t)e * DHID_ * DM_;
    const unsigned short* VT = VTa + (size_t)e * DHID_ * DM_;
    __shared__ unsigned short As[128 * 64];
    __shared__ int rtok[128];
    const int tid = threadIdx.x;
    const int wid = tid >> 6, lane = tid & 63;
    if (tid < 128) {
        int r = m0 + tid;
        rtok[tid] = (r < ce) ? ptok[base + r] : ptok[base + ce - 1];
    }
    __syncthreads();

    const unsigned short* aSrc[4]; int aWr[4];
    #pragma unroll
    for (int i = 0; i < 4; ++i) {
        int idx = tid + 256 * i;
        int row = idx >> 3, c8 = idx & 7;
        aSrc[i] = X1b + (size_t)rtok[row] * DM_ + c8 * 8;
        aWr[i] = (row * 128 + c8 * 16) ^ ((row & 7) << 4);
    }
    const int wr = wid >> 1, wc = wid & 1;
    // B fragment layout: col=lane&15 (row of BT), k=(lane>>4)*8+[0..8)
    const unsigned short* wF[2]; const unsigned short* vF[2];
    #pragma unroll
    for (int t = 0; t < 2; ++t) {
        int row = n0 + wc * 32 + t * 16 + (lane & 15);
        wF[t] = WT + (size_t)row * DM_ + (lane >> 4) * 8;
        vF[t] = VT + (size_t)row * DM_ + (lane >> 4) * 8;
    }
    int ra[2][4];
    #pragma unroll
    for (int kk = 0; kk < 2; ++kk)
        #pragma unroll
        for (int t = 0; t < 4; ++t) {
            int rowa = wr * 64 + t * 16 + (lane & 15);
            int kb = kk * 64 + (lane >> 4) * 16;
            ra[kk][t] = (rowa * 128 + kb) ^ ((rowa & 7) << 4);
        }
    const f32x4 zero = {0.f, 0.f, 0.f, 0.f};
    f32x4 accw[4][2], accv[4][2];
    #pragma unroll
    for (int i = 0; i < 4; ++i)
        #pragma unroll
        for (int j = 0; j < 2; ++j) { accw[i][j] = zero; accv[i][j] = zero; }

    short8 sa[4];
    #pragma unroll
    for (int i = 0; i < 4; ++i) sa[i] = *(const short8*)(aSrc[i]);
    const int nk = DM_ >> 6;
    for (int kt = 0; kt < nk; ++kt) {
        #pragma unroll
        for (int i = 0; i < 4; ++i) *(short8*)((char*)As + aWr[i]) = sa[i];
        // B frags for this kt (global, no barrier dependency -> overlap with A drain)
        short8 bw[2][2], bv[2][2];
        const int ke = kt << 6;
        #pragma unroll
        for (int kk = 0; kk < 2; ++kk)
            #pragma unroll
            for (int t = 0; t < 2; ++t) {
                bw[kk][t] = *(const short8*)(wF[t] + ke + kk * 32);
                bv[kk][t] = *(const short8*)(vF[t] + ke + kk * 32);
            }
        __syncthreads();
        if (kt + 1 < nk) {
            int ko = (kt + 1) << 6;
            #pragma unroll
            for (int i = 0; i < 4; ++i) sa[i] = *(const short8*)(aSrc[i] + ko);
        }
        #pragma unroll
        for (int kk = 0; kk < 2; ++kk) {
            short8 af[4];
            #pragma unroll
            for (int t = 0; t < 4; ++t) af[t] = *(const short8*)((const char*)As + ra[kk][t]);
            #pragma unroll
            for (int i = 0; i < 4; ++i)
                #pragma unroll
                for (int j = 0; j < 2; ++j) {
                    accw[i][j] = __builtin_amdgcn_mfma_f32_16x16x32_bf16(af[i], bw[kk][j], accw[i][j], 0, 0, 0);
                    accv[i][j] = __builtin_amdgcn_mfma_f32_16x16x32_bf16(af[i], bv[kk][j], accv[i][j], 0, 0, 0);
                }
        }
        __syncthreads();
    }
    const int cl = lane & 15, g4 = lane >> 4;
    #pragma unroll
    for (int i = 0; i < 4; ++i)
        #pragma unroll
        for (int j = 0; j < 2; ++j)
            #pragma unroll
            for (int r = 0; r < 4; ++r) {
                int rl = m0 + wr * 64 + i * 16 + g4 * 4 + r;
                if (rl < ce) {
                    float a = accw[i][j][r], b = accv[i][j][r];
                    float h = a * (b / (1.f + __expf(-b)));
                    H[(size_t)(base + rl) * DHID_ + n0 + wc * 32 + j * 16 + cl] = f2bf(h);
                }
            }
}

// ============== MoE down: PY f32 = H bf16 @ WoT^T, 128x128, prefetch ===============
__global__ __launch_bounds__(256) void moe_down_mfma(
        const unsigned short* __restrict__ H, const unsigned short* __restrict__ WoTa,
        float* __restrict__ PY,
        const int* __restrict__ cnt, const int* __restrict__ offs)
{
    const int e = blockIdx.z;
    const int ce = cnt[e];
    const int m0 = blockIdx.y * 128;
    if (m0 >= ce) return;
    const int n0 = blockIdx.x * 128;
    const int base = offs[e];
    const unsigned short* WoT = WoTa + (size_t)e * DM_ * DHID_;
    __shared__ unsigned short As[128 * 64];
    __shared__ unsigned short Bs[128 * 64];
    const int tid = threadIdx.x;
    const int wid = tid >> 6, lane = tid & 63;

    const unsigned short* aSrc[4]; const unsigned short* bSrc[4]; int sWr[4];
    #pragma unroll
    for (int i = 0; i < 4; ++i) {
        int idx = tid + 256 * i;
        int row = idx >> 3, c8 = idx & 7;
        int r = m0 + row; if (r >= ce) r = ce - 1;
        aSrc[i] = H + (size_t)(base + r) * DHID_ + c8 * 8;
        bSrc[i] = WoT + (size_t)(n0 + row) * DHID_ + c8 * 8;
        sWr[i] = (row * 128 + c8 * 16) ^ ((row & 7) << 4);
    }
    const int wr = wid >> 1, wc = wid & 1;
    int ra[2][4], rb[2][4];
    #pragma unroll
    for (int kk = 0; kk < 2; ++kk) {
        #pragma unroll
        for (int t = 0; t < 4; ++t) {
            int kb = kk * 64 + (lane >> 4) * 16;
            int rowa = wr * 64 + t * 16 + (lane & 15);
            ra[kk][t] = (rowa * 128 + kb) ^ ((rowa & 7) << 4);
            int rowb = wc * 64 + t * 16 + (lane & 15);
            rb[kk][t] = (rowb * 128 + kb) ^ ((rowb & 7) << 4);
        }
    }
    const f32x4 zero = {0.f, 0.f, 0.f, 0.f};
    f32x4 acc[4][4];
    #pragma unroll
    for (int i = 0; i < 4; ++i)
        #pragma unroll
        for (int j = 0; j < 4; ++j) acc[i][j] = zero;

    short8 sa[4], sb[4];
    #pragma unroll
    for (int i = 0; i < 4; ++i) { sa[i] = *(const short8*)(aSrc[i]); sb[i] = *(const short8*)(bSrc[i]); }
    const int nk = DHID_ >> 6;
    for (int kt = 0; kt < nk; ++kt) {
        #pragma unroll
        for (int i = 0; i < 4; ++i) {
            *(short8*)((char*)As + sWr[i]) = sa[i];
            *(short8*)((char*)Bs + sWr[i]) = sb[i];
        }
        __syncthreads();
        if (kt + 1 < nk) {
            int ko = (kt + 1) << 6;
            #pragma unroll
            for (int i = 0; i < 4; ++i) { sa[i] = *(const short8*)(aSrc[i] + ko); sb[i] = *(const short8*)(bSrc[i] + ko); }
        }
        #pragma unroll
        for (int kk = 0; kk < 2; ++kk) {
            short8 af[4], bfr[4];
            #pragma unroll
            for (int t = 0; t < 4; ++t) {
                af[t]  = *(const short8*)((const char*)As + ra[kk][t]);
                bfr[t] = *(const short8*)((const char*)Bs + rb[kk][t]);
            }
            #pragma unroll
            for (int i = 0; i < 4; ++i)
                #pragma unroll
                for (int j = 0; j < 4; ++j)
                    acc[i][j] = __builtin_amdgcn_mfma_f32_16x16x32_bf16(af[i], bfr[j], acc[i][j], 0, 0, 0);
        }
        __syncthreads();
    }
    const int cl = lane & 15, g4 = lane >> 4;
    #pragma unroll
    for (int i = 0; i < 4; ++i)
        #pragma unroll
        for (int j = 0; j < 4; ++j)
            #pragma unroll
            for (int r = 0; r < 4; ++r) {
                int rl = m0 + wr * 64 + i * 16 + g4 * 4 + r;
                if (rl < ce)
                    PY[(size_t)(base + rl) * DM_ + n0 + wc * 64 + j * 16 + cl] = acc[i][j][r];
            }
}

// ---------------- combine -----------------------------------------------------------
__global__ __launch_bounds__(256) void moe_combine(const float* __restrict__ PY,
        const int* __restrict__ pidx, const float* __restrict__ gates,
        float* __restrict__ MO)
{
    int n = blockIdx.x, tid = threadIdx.x;
    int p0 = pidx[n * 2], p1 = pidx[n * 2 + 1];
    float g0 = gates[n * 2], g1 = gates[n * 2 + 1];
    #pragma unroll
    for (int i = 0; i < 4; ++i) {
        int d = tid + i * 256;
        MO[(size_t)n * DM_ + d] = g0 * PY[(size_t)p0 * DM_ + d] + g1 * PY[(size_t)p1 * DM_ + d];
    }
}

extern "C" void kernel_launch(void* const* d_in, const int* in_sizes, int n_in,
                              void* d_out, int out_size, void* d_ws, size_t ws_size,
                              hipStream_t stream)
{
    const float* x      = (const float*)d_in[0];
    const float* cosb   = (const float*)d_in[1];
    const float* sinb   = (const float*)d_in[2];
    const float* ln1g   = (const float*)d_in[3];
    const float* ln1b   = (const float*)d_in[4];
    const float* ln2g   = (const float*)d_in[5];
    const float* ln2b   = (const float*)d_in[6];
    const float* ln3g   = (const float*)d_in[7];
    const float* ln3b   = (const float*)d_in[8];
    const float* Lat    = (const float*)d_in[9];
    const float* Wq_lat = (const float*)d_in[10];
    const float* Wk_in  = (const float*)d_in[11];
    const float* Wv_in  = (const float*)d_in[12];
    const float* Wq_in  = (const float*)d_in[13];
    const float* Wk_lat = (const float*)d_in[14];
    const float* Wv_lat = (const float*)d_in[15];
    const float* Wout   = (const float*)d_in[16];
    const float* rW     = (const float*)d_in[17];
    const float* rb     = (const float*)d_in[18];
    const float* eW     = (const float*)d_in[19];
    const float* eV     = (const float*)d_in[20];
    const float* eWo    = (const float*)d_in[21];
    const float* linW   = (const float*)d_in[22];
    const float* linb   = (const float*)d_in[23];
    float* out = (float*)d_out;

    float* ws = (float*)d_ws;
    const size_t M1 = 1024 * 1024;
    float* buf0 = ws;                 // K-proj / MoE out
    float* buf1 = ws + 4 * M1;        // V-proj / attn out / X2
    float* buf2 = ws + 8 * M1;        // Q-proj(rope) / X1
    float* buf3 = ws + 12 * M1;       // S1 / final-linear out
    size_t off = 16 * M1;
    float* qlat = ws + off; off += 65536;
    float* qlb  = ws + off; off += 131072;
    float* klb  = ws + off; off += 131072;
    float* vlb  = ws + off; off += 131072;
    float* s2b  = ws + off; off += 131072;
    float* z2b  = ws + off; off += 131072;
    float* kzb  = ws + off; off += 131072;
    float* vzb  = ws + off; off += 131072;
    float* gates = ws + off; off += 8192;
    int* iarea = (int*)(ws + off); off += 32768;
    int* topi   = iarea;
    int* counts = iarea + 8192;
    int* offs   = iarea + 8200;
    int* fill   = iarea + 8208;
    int* ptok   = iarea + 8216;
    int* pidx   = iarea + 16408;
    unsigned short* zb_b  = (unsigned short*)(ws + off); off += 65536;
    unsigned short* z2b_b = (unsigned short*)(ws + off); off += 65536;
    unsigned short* latb  = (unsigned short*)(ws + off); off += 32768;
    unsigned short* x1b   = (unsigned short*)(ws + off); off += 2 * M1;
    unsigned short* WkT   = (unsigned short*)(ws + off); off += 3 * (M1 / 2);
    unsigned short* WoutT = (unsigned short*)(ws + off); off += M1 / 2;
    unsigned short* linWT = (unsigned short*)(ws + off); off += M1 / 2;
    unsigned short* WlatT = (unsigned short*)(ws + off); off += 3 * (M1 / 2);

    unsigned short* Hbuf  = (unsigned short*)(ws + 24 * M1);
    unsigned short* actb  = (unsigned short*)(ws + 24 * M1);   // alias
    unsigned short* x2b   = (unsigned short*)(ws + 24 * M1);   // alias
    float* pvpart         = ws + 26 * M1;
    unsigned short* eWT   = (unsigned short*)(ws + 40 * M1);
    unsigned short* eVT   = (unsigned short*)(ws + 56 * M1);
    unsigned short* eWoT  = eWT;
    float* PY             = ws + 56 * M1;

    dim3 blk(256);

    zero_counts<<<1, 64, 0, stream>>>(counts);

    // weight prep
    tconv3<<<dim3(16, 16, 3), blk, 0, stream>>>(Wk_in, Wv_in, Wq_in, WkT);
    tconv<<<dim3(16, 16, 1), blk, 0, stream>>>(Wout, WoutT, 1024, 1024);
    tconv<<<dim3(16, 16, 1), blk, 0, stream>>>(linW, linWT, 1024, 1024);
    tconv3<<<dim3(16, 16, 3), blk, 0, stream>>>(Wq_lat, Wk_lat, Wv_lat, WlatT);
    tconv<<<dim3(64, 16, 8), blk, 0, stream>>>(eW, eWT, 1024, 4096);
    tconv<<<dim3(64, 16, 8), blk, 0, stream>>>(eV, eVT, 1024, 4096);
    c2b<<<2048, blk, 0, stream>>>(x, actb, 524288);
    c2b<<<32, blk, 0, stream>>>(Lat, latb, 8192);

    // qlat = Lat @ Wq_lat
    gemm_lat<<<dim3(16, 1), blk, 0, stream>>>(latb, WlatT, (int)M1, qlat, 0, 64);

    // projections (K rope z=0, V plain z=1, Q rope z=2)
    gemm_proj3<<<dim3(8, 32, 3), blk, 0, stream>>>(actb, WkT, buf0, cosb, sinb);

    // attn1: latents query tokens
    attn_scores<<<dim3(32, 1, 32), blk, 0, stream>>>(buf3, qlat, buf0, 64, 2048, 0, 2048, 0.125f);
    softmax_rows<<<2048, blk, 0, stream>>>(buf3, 2048);
    pv_split<<<dim3(8, 32), blk, 0, stream>>>(pvpart, buf3, buf1);
    pv_combine<<<32, blk, 0, stream>>>(pvpart, zb_b);

    // attn2: latents self-attention (fused)
    gemm_lat<<<dim3(16, 3), blk, 0, stream>>>(zb_b, WlatT, (int)M1, qlb, 131072, 128);
    fused_attn64<<<dim3(1, 32), blk, 0, stream>>>(z2b_b, qlb, klb, vlb, 64);

    // attn3: tokens query latents (fused)
    gemm_lat<<<dim3(16, 2), blk, 0, stream>>>(z2b_b, WlatT + M1, (int)M1, kzb, 131072, 128);
    fused_attn64<<<dim3(32, 32), blk, 0, stream>>>(actb, buf2, kzb, vzb, 2048);
    gemm_bf16_128<<<dim3(8, 32), blk, 0, stream>>>(actb, WoutT, buf1, 4096, 1024, 1024);

    // residual 1: X1 = LN1(x) + attn
    ln_add_dual<<<4096, blk, 0, stream>>>(x, ln1g, ln1b, buf1, buf2, x1b);

    // MoE
    router_kernel<<<4096, blk, 0, stream>>>(buf2, rW, rb, topi, gates, counts);
    router_offsets<<<1, 64, 0, stream>>>(counts, offs, fill);
    router_scatter<<<16, blk, 0, stream>>>(topi, fill, offs, ptok, pidx);
    moe_up_mfma<<<dim3(64, 32, 8), blk, 0, stream>>>(x1b, eWT, eVT, Hbuf, counts, offs, ptok);
    tconv<<<dim3(16, 64, 8), blk, 0, stream>>>(eWo, eWoT, 4096, 1024);
    moe_down_mfma<<<dim3(8, 32, 8), blk, 0, stream>>>(Hbuf, eWoT, PY, counts, offs);
    moe_combine<<<4096, blk, 0, stream>>>(PY, pidx, gates, buf0);

    // residual 2: X2 = LN2(X1) + MoE
    ln_add_dual<<<4096, blk, 0, stream>>>(buf2, ln2g, ln2b, buf0, buf1, x2b);

    // final linear + residual 3
    gemm_bf16_128<<<dim3(8, 32), blk, 0, stream>>>(x2b, linWT, buf3, 4096, 1024, 1024);
    ln_final<<<4096, blk, 0, stream>>>(buf1, ln3g, ln3b, buf3, linb, out);
}

// Round 11
// 993.459 us; speedup vs baseline: 1.1078x; 1.1078x over previous
//
#include <hip/hip_runtime.h>
#include <hip/hip_bf16.h>
#include <math.h>

typedef __hip_bfloat16 bf16;
typedef __attribute__((ext_vector_type(8))) short short8;
typedef __attribute__((ext_vector_type(8))) unsigned short ushort8;
typedef __attribute__((ext_vector_type(4))) float f32x4;

#define NT_   2048
#define NTOK_ 4096
#define DM_   1024
#define DHID_ 4096
#define NEXP_ 8

__device__ __forceinline__ unsigned short f2bf(float f) {
    unsigned u = __float_as_uint(f);
    u = u + 0x7FFF + ((u >> 16) & 1);
    return (unsigned short)(u >> 16);
}

// ============================ fp32 -> bf16 convert (flat) ==========================
__global__ __launch_bounds__(256) void c2b(const float* __restrict__ in,
        unsigned short* __restrict__ out, int n8)
{
    int i = blockIdx.x * 256 + threadIdx.x;
    if (i >= n8) return;
    const float4 v0 = *(const float4*)(in + (size_t)i * 8);
    const float4 v1 = *(const float4*)(in + (size_t)i * 8 + 4);
    ushort8 o;
    o[0] = f2bf(v0.x); o[1] = f2bf(v0.y); o[2] = f2bf(v0.z); o[3] = f2bf(v0.w);
    o[4] = f2bf(v1.x); o[5] = f2bf(v1.y); o[6] = f2bf(v1.z); o[7] = f2bf(v1.w);
    *(ushort8*)(out + (size_t)i * 8) = o;
}

// ================== transpose+convert: in f32 [R][C] -> out bf16 [C][R] ============
__global__ __launch_bounds__(256) void tconv(const float* __restrict__ in,
        unsigned short* __restrict__ out, int R, int C)
{
    __shared__ float t[64][65];
    const size_t mofs = (size_t)blockIdx.z * R * C;
    const int r0 = blockIdx.y * 64, c0 = blockIdx.x * 64;
    const int tid = threadIdx.x;
    const int lr = tid >> 4, lc4 = (tid & 15) * 4;
    #pragma unroll
    for (int i = 0; i < 4; ++i) {
        float4 v = *(const float4*)(in + mofs + (size_t)(r0 + lr + i * 16) * C + c0 + lc4);
        t[lr + i * 16][lc4 + 0] = v.x; t[lr + i * 16][lc4 + 1] = v.y;
        t[lr + i * 16][lc4 + 2] = v.z; t[lr + i * 16][lc4 + 3] = v.w;
    }
    __syncthreads();
    const int oc = tid >> 2;
    const int j0 = (tid & 3) * 16;
    ushort8 o0, o1;
    #pragma unroll
    for (int j = 0; j < 8; ++j)  o0[j] = f2bf(t[j0 + j][oc]);
    #pragma unroll
    for (int j = 0; j < 8; ++j)  o1[j] = f2bf(t[j0 + 8 + j][oc]);
    size_t ob = mofs + (size_t)(c0 + oc) * R + r0 + j0;
    *(ushort8*)(out + ob) = o0;
    *(ushort8*)(out + ob + 8) = o1;
}

// three separate sources (batched over z), same R=C=1024
__global__ __launch_bounds__(256) void tconv3(const float* __restrict__ s0,
        const float* __restrict__ s1, const float* __restrict__ s2,
        unsigned short* __restrict__ out)
{
    __shared__ float t[64][65];
    const float* in = blockIdx.z == 0 ? s0 : (blockIdx.z == 1 ? s1 : s2);
    unsigned short* o = out + (size_t)blockIdx.z * DM_ * DM_;
    const int r0 = blockIdx.y * 64, c0 = blockIdx.x * 64;
    const int tid = threadIdx.x;
    const int lr = tid >> 4, lc4 = (tid & 15) * 4;
    #pragma unroll
    for (int i = 0; i < 4; ++i) {
        float4 v = *(const float4*)(in + (size_t)(r0 + lr + i * 16) * DM_ + c0 + lc4);
        t[lr + i * 16][lc4 + 0] = v.x; t[lr + i * 16][lc4 + 1] = v.y;
        t[lr + i * 16][lc4 + 2] = v.z; t[lr + i * 16][lc4 + 3] = v.w;
    }
    __syncthreads();
    const int oc = tid >> 2;
    const int j0 = (tid & 3) * 16;
    ushort8 o0, o1;
    #pragma unroll
    for (int j = 0; j < 8; ++j)  o0[j] = f2bf(t[j0 + j][oc]);
    #pragma unroll
    for (int j = 0; j < 8; ++j)  o1[j] = f2bf(t[j0 + 8 + j][oc]);
    size_t ob = (size_t)(c0 + oc) * DM_ + r0 + j0;
    *(ushort8*)(o + ob) = o0;
    *(ushort8*)(o + ob + 8) = o1;
}

// ====== eW+eV transpose in one launch: z<8 -> eW[z], else eV[z-8]; R=1024 C=4096 ====
__global__ __launch_bounds__(256) void tconvEV(const float* __restrict__ s0,
        const float* __restrict__ s1, unsigned short* __restrict__ out)
{
    __shared__ float t[64][65];
    const int z = blockIdx.z;
    const size_t rc = (size_t)DM_ * DHID_;
    const float* in = (z < 8) ? (s0 + (size_t)z * rc) : (s1 + (size_t)(z - 8) * rc);
    unsigned short* o = out + (size_t)z * rc;
    const int r0 = blockIdx.y * 64, c0 = blockIdx.x * 64;
    const int tid = threadIdx.x;
    const int lr = tid >> 4, lc4 = (tid & 15) * 4;
    #pragma unroll
    for (int i = 0; i < 4; ++i) {
        float4 v = *(const float4*)(in + (size_t)(r0 + lr + i * 16) * DHID_ + c0 + lc4);
        t[lr + i * 16][lc4 + 0] = v.x; t[lr + i * 16][lc4 + 1] = v.y;
        t[lr + i * 16][lc4 + 2] = v.z; t[lr + i * 16][lc4 + 3] = v.w;
    }
    __syncthreads();
    const int oc = tid >> 2;
    const int j0 = (tid & 3) * 16;
    ushort8 o0, o1;
    #pragma unroll
    for (int j = 0; j < 8; ++j)  o0[j] = f2bf(t[j0 + j][oc]);
    #pragma unroll
    for (int j = 0; j < 8; ++j)  o1[j] = f2bf(t[j0 + 8 + j][oc]);
    size_t ob = (size_t)(c0 + oc) * DM_ + r0 + j0;
    *(ushort8*)(o + ob) = o0;
    *(ushort8*)(o + ob + 8) = o1;
}

// =========== MFMA GEMM: C f32[M,N] = A bf16[M,K] @ (BT bf16[N,K])^T ================
__global__ __launch_bounds__(256) void gemm_bf16_128(
        const unsigned short* __restrict__ A, const unsigned short* __restrict__ BT,
        float* __restrict__ C, int M, int N, int K)
{
    __shared__ unsigned short As[128 * 64];
    __shared__ unsigned short Bs[128 * 64];
    const int tid = threadIdx.x;
    const int wid = tid >> 6, lane = tid & 63;
    const int m0 = blockIdx.y * 128, n0 = blockIdx.x * 128;

    const unsigned short* aSrc[4]; const unsigned short* bSrc[4]; int sWr[4];
    #pragma unroll
    for (int i = 0; i < 4; ++i) {
        int idx = tid + 256 * i;
        int row = idx >> 3, c8 = idx & 7;
        int ar = m0 + row; if (ar >= M) ar = M - 1;
        aSrc[i] = A + (size_t)ar * K + c8 * 8;
        bSrc[i] = BT + (size_t)(n0 + row) * K + c8 * 8;
        sWr[i] = (row * 128 + c8 * 16) ^ ((row & 7) << 4);
    }
    const int wr = wid >> 1, wc = wid & 1;
    int ra[2][4], rb[2][4];
    #pragma unroll
    for (int kk = 0; kk < 2; ++kk) {
        #pragma unroll
        for (int t = 0; t < 4; ++t) {
            int kb = kk * 64 + (lane >> 4) * 16;
            int rowa = wr * 64 + t * 16 + (lane & 15);
            ra[kk][t] = (rowa * 128 + kb) ^ ((rowa & 7) << 4);
            int rowb = wc * 64 + t * 16 + (lane & 15);
            rb[kk][t] = (rowb * 128 + kb) ^ ((rowb & 7) << 4);
        }
    }
    const f32x4 zero = {0.f, 0.f, 0.f, 0.f};
    f32x4 acc[4][4];
    #pragma unroll
    for (int i = 0; i < 4; ++i)
        #pragma unroll
        for (int j = 0; j < 4; ++j) acc[i][j] = zero;

    short8 sa[4], sb[4];
    #pragma unroll
    for (int i = 0; i < 4; ++i) { sa[i] = *(const short8*)(aSrc[i]); sb[i] = *(const short8*)(bSrc[i]); }
    const int nk = K >> 6;
    for (int kt = 0; kt < nk; ++kt) {
        #pragma unroll
        for (int i = 0; i < 4; ++i) {
            *(short8*)((char*)As + sWr[i]) = sa[i];
            *(short8*)((char*)Bs + sWr[i]) = sb[i];
        }
        __syncthreads();
        if (kt + 1 < nk) {
            int ko = (kt + 1) << 6;
            #pragma unroll
            for (int i = 0; i < 4; ++i) { sa[i] = *(const short8*)(aSrc[i] + ko); sb[i] = *(const short8*)(bSrc[i] + ko); }
        }
        #pragma unroll
        for (int kk = 0; kk < 2; ++kk) {
            short8 af[4], bfr[4];
            #pragma unroll
            for (int t = 0; t < 4; ++t) {
                af[t]  = *(const short8*)((const char*)As + ra[kk][t]);
                bfr[t] = *(const short8*)((const char*)Bs + rb[kk][t]);
            }
            #pragma unroll
            for (int i = 0; i < 4; ++i)
                #pragma unroll
                for (int j = 0; j < 4; ++j)
                    acc[i][j] = __builtin_amdgcn_mfma_f32_16x16x32_bf16(af[i], bfr[j], acc[i][j], 0, 0, 0);
        }
        __syncthreads();
    }
    const int cl = lane & 15, g4 = lane >> 4;
    #pragma unroll
    for (int i = 0; i < 4; ++i)
        #pragma unroll
        for (int j = 0; j < 4; ++j)
            #pragma unroll
            for (int r = 0; r < 4; ++r) {
                int rr = m0 + wr * 64 + i * 16 + g4 * 4 + r;
                if (rr < M) C[(size_t)rr * N + n0 + wc * 64 + j * 16 + cl] = acc[i][j][r];
            }
}

// ====== batched projections x@{Wk,Wv,Wq} with fused RoPE on z=0 (K) and z=2 (Q) ====
__global__ __launch_bounds__(256) void gemm_proj3(
        const unsigned short* __restrict__ A, const unsigned short* __restrict__ BT0,
        float* __restrict__ C0, const float* __restrict__ cosb,
        const float* __restrict__ sinb)
{
    const int z = blockIdx.z;
    const unsigned short* BT = BT0 + (size_t)z * DM_ * DM_;
    float* C = C0 + (size_t)z * NTOK_ * DM_;
    const bool doRope = (z != 1);
    __shared__ unsigned short As[128 * 64];
    __shared__ unsigned short Bs[128 * 64];
    const int tid = threadIdx.x;
    const int wid = tid >> 6, lane = tid & 63;
    const int m0 = blockIdx.y * 128, n0 = blockIdx.x * 128;
    const int K = DM_, N = DM_;

    const unsigned short* aSrc[4]; const unsigned short* bSrc[4]; int sWr[4];
    #pragma unroll
    for (int i = 0; i < 4; ++i) {
        int idx = tid + 256 * i;
        int row = idx >> 3, c8 = idx & 7;
        aSrc[i] = A + (size_t)(m0 + row) * K + c8 * 8;
        bSrc[i] = BT + (size_t)(n0 + row) * K + c8 * 8;
        sWr[i] = (row * 128 + c8 * 16) ^ ((row & 7) << 4);
    }
    const int wr = wid >> 1, wc = wid & 1;
    int ra[2][4], rb[2][4];
    #pragma unroll
    for (int kk = 0; kk < 2; ++kk) {
        #pragma unroll
        for (int t = 0; t < 4; ++t) {
            int kb = kk * 64 + (lane >> 4) * 16;
            int rowa = wr * 64 + t * 16 + (lane & 15);
            ra[kk][t] = (rowa * 128 + kb) ^ ((rowa & 7) << 4);
            int rowb = wc * 64 + t * 16 + (lane & 15);
            rb[kk][t] = (rowb * 128 + kb) ^ ((rowb & 7) << 4);
        }
    }
    const f32x4 zero = {0.f, 0.f, 0.f, 0.f};
    f32x4 acc[4][4];
    #pragma unroll
    for (int i = 0; i < 4; ++i)
        #pragma unroll
        for (int j = 0; j < 4; ++j) acc[i][j] = zero;

    short8 sa[4], sb[4];
    #pragma unroll
    for (int i = 0; i < 4; ++i) { sa[i] = *(const short8*)(aSrc[i]); sb[i] = *(const short8*)(bSrc[i]); }
    const int nk = K >> 6;
    for (int kt = 0; kt < nk; ++kt) {
        #pragma unroll
        for (int i = 0; i < 4; ++i) {
            *(short8*)((char*)As + sWr[i]) = sa[i];
            *(short8*)((char*)Bs + sWr[i]) = sb[i];
        }
        __syncthreads();
        if (kt + 1 < nk) {
            int ko = (kt + 1) << 6;
            #pragma unroll
            for (int i = 0; i < 4; ++i) { sa[i] = *(const short8*)(aSrc[i] + ko); sb[i] = *(const short8*)(bSrc[i] + ko); }
        }
        #pragma unroll
        for (int kk = 0; kk < 2; ++kk) {
            short8 af[4], bfr[4];
            #pragma unroll
            for (int t = 0; t < 4; ++t) {
                af[t]  = *(const short8*)((const char*)As + ra[kk][t]);
                bfr[t] = *(const short8*)((const char*)Bs + rb[kk][t]);
            }
            #pragma unroll
            for (int i = 0; i < 4; ++i)
                #pragma unroll
                for (int j = 0; j < 4; ++j)
                    acc[i][j] = __builtin_amdgcn_mfma_f32_16x16x32_bf16(af[i], bfr[j], acc[i][j], 0, 0, 0);
        }
        __syncthreads();
    }
    const int cl = lane & 15, g4 = lane >> 4;
    #pragma unroll
    for (int i = 0; i < 4; ++i)
        #pragma unroll
        for (int j = 0; j < 4; ++j) {
            const int cc = n0 + wc * 64 + j * 16 + cl;
            const int ii = (cc & 63) >> 1;
            const bool even = (cc & 1) == 0;
            #pragma unroll
            for (int r = 0; r < 4; ++r) {
                const int rr = m0 + wr * 64 + i * 16 + g4 * 4 + r;
                float v = acc[i][j][r];
                float p = __shfl_xor(v, 1, 64);
                float o = v;
                if (doRope) {
                    const int t = rr & (NT_ - 1);
                    float cv = cosb[t * 32 + ii], sv = sinb[t * 32 + ii];
                    o = even ? (v * cv - p * sv) : (p * sv + v * cv);
                }
                C[(size_t)rr * N + cc] = o;
            }
        }
}

// ====== small latent GEMM, batched: C[z] f32[M,1024] = A bf16[M,1024] @ BT[z]^T ====
__global__ __launch_bounds__(256) void gemm_lat(
        const unsigned short* __restrict__ A, const unsigned short* __restrict__ BT0,
        int btStride, float* __restrict__ C0, int cStride, int M)
{
    const int z = blockIdx.y;
    const unsigned short* BT = BT0 + (size_t)z * btStride;
    float* C = C0 + (size_t)z * cStride;
    const int n0 = blockIdx.x * 64;
    __shared__ unsigned short As[128 * 64];
    __shared__ unsigned short Bs[64 * 64];
    const int tid = threadIdx.x;
    const int wid = tid >> 6, lane = tid & 63;

    const unsigned short* aSrc[4]; int aWr[4];
    #pragma unroll
    for (int i = 0; i < 4; ++i) {
        int idx = tid + 256 * i;
        int row = idx >> 3, c8 = idx & 7;
        int ar = row; if (ar >= M) ar = M - 1;
        aSrc[i] = A + (size_t)ar * DM_ + c8 * 8;
        aWr[i] = (row * 128 + c8 * 16) ^ ((row & 7) << 4);
    }
    const unsigned short* bSrc[2]; int bWr[2];
    #pragma unroll
    for (int i = 0; i < 2; ++i) {
        int idx = tid + 256 * i;
        int row = idx >> 3, c8 = idx & 7;
        bSrc[i] = BT + (size_t)(n0 + row) * DM_ + c8 * 8;
        bWr[i] = (row * 128 + c8 * 16) ^ ((row & 7) << 4);
    }
    const int wr = wid >> 1, wc = wid & 1;
    int ra[2][4], rb[2][2];
    #pragma unroll
    for (int kk = 0; kk < 2; ++kk) {
        #pragma unroll
        for (int t = 0; t < 4; ++t) {
            int rowa = wr * 64 + t * 16 + (lane & 15);
            int kb = kk * 64 + (lane >> 4) * 16;
            ra[kk][t] = (rowa * 128 + kb) ^ ((rowa & 7) << 4);
        }
        #pragma unroll
        for (int t = 0; t < 2; ++t) {
            int rowb = wc * 32 + t * 16 + (lane & 15);
            int kb = kk * 64 + (lane >> 4) * 16;
            rb[kk][t] = (rowb * 128 + kb) ^ ((rowb & 7) << 4);
        }
    }
    const f32x4 zero = {0.f, 0.f, 0.f, 0.f};
    f32x4 acc[4][2];
    #pragma unroll
    for (int i = 0; i < 4; ++i)
        #pragma unroll
        for (int j = 0; j < 2; ++j) acc[i][j] = zero;

    short8 sa[4], sb[2];
    #pragma unroll
    for (int i = 0; i < 4; ++i) sa[i] = *(const short8*)(aSrc[i]);
    #pragma unroll
    for (int i = 0; i < 2; ++i) sb[i] = *(const short8*)(bSrc[i]);
    const int nk = DM_ >> 6;
    for (int kt = 0; kt < nk; ++kt) {
        #pragma unroll
        for (int i = 0; i < 4; ++i) *(short8*)((char*)As + aWr[i]) = sa[i];
        #pragma unroll
        for (int i = 0; i < 2; ++i) *(short8*)((char*)Bs + bWr[i]) = sb[i];
        __syncthreads();
        if (kt + 1 < nk) {
            int ko = (kt + 1) << 6;
            #pragma unroll
            for (int i = 0; i < 4; ++i) sa[i] = *(const short8*)(aSrc[i] + ko);
            #pragma unroll
            for (int i = 0; i < 2; ++i) sb[i] = *(const short8*)(bSrc[i] + ko);
        }
        #pragma unroll
        for (int kk = 0; kk < 2; ++kk) {
            short8 af[4], bf2[2];
            #pragma unroll
            for (int t = 0; t < 4; ++t) af[t] = *(const short8*)((const char*)As + ra[kk][t]);
            #pragma unroll
            for (int t = 0; t < 2; ++t) bf2[t] = *(const short8*)((const char*)Bs + rb[kk][t]);
            #pragma unroll
            for (int i = 0; i < 4; ++i)
                #pragma unroll
                for (int j = 0; j < 2; ++j)
                    acc[i][j] = __builtin_amdgcn_mfma_f32_16x16x32_bf16(af[i], bf2[j], acc[i][j], 0, 0, 0);
        }
        __syncthreads();
    }
    const int cl = lane & 15, g4 = lane >> 4;
    #pragma unroll
    for (int i = 0; i < 4; ++i)
        #pragma unroll
        for (int j = 0; j < 2; ++j)
            #pragma unroll
            for (int r = 0; r < 4; ++r) {
                int rl = wr * 64 + i * 16 + g4 * 4 + r;
                if (rl < M)
                    C[(size_t)rl * DM_ + n0 + wc * 32 + j * 16 + cl] = acc[i][j][r];
            }
}

// ---------------- attention scores (attn1 only) -------------------------------------
__global__ __launch_bounds__(256) void attn_scores(float* __restrict__ S,
        const float* __restrict__ Q, const float* __restrict__ Km,
        int M, int T, int q_bs, int k_bs, float scale)
{
    const int bh = blockIdx.z, b = bh >> 4, h = bh & 15;
    const int t0 = blockIdx.x * 64, q0 = blockIdx.y * 64;
    __shared__ float Qs[64][65], Ks[64][65];
    const int tid = threadIdx.x;
    const int lr = tid >> 2, lc = (tid & 3) * 16;
    {
        int q = q0 + lr;
        if (q < M) {
            const float* Qp = Q + ((size_t)q_bs * b + q) * DM_ + h * 64 + lc;
            #pragma unroll
            for (int j = 0; j < 16; ++j) Qs[lr][lc + j] = Qp[j];
        } else {
            #pragma unroll
            for (int j = 0; j < 16; ++j) Qs[lr][lc + j] = 0.f;
        }
        const float* Kp = Km + ((size_t)k_bs * b + t0 + lr) * DM_ + h * 64 + lc;
        #pragma unroll
        for (int j = 0; j < 16; ++j) Ks[lr][lc + j] = Kp[j];
    }
    __syncthreads();
    const int ty = tid >> 4, tx = tid & 15;
    float acc[4][4] = {};
    for (int d = 0; d < 64; ++d) {
        float a[4], kk[4];
        #pragma unroll
        for (int i = 0; i < 4; ++i) a[i] = Qs[ty * 4 + i][d];
        #pragma unroll
        for (int j = 0; j < 4; ++j) kk[j] = Ks[tx * 4 + j][d];
        #pragma unroll
        for (int i = 0; i < 4; ++i)
            #pragma unroll
            for (int j = 0; j < 4; ++j) acc[i][j] += a[i] * kk[j];
    }
    #pragma unroll
    for (int i = 0; i < 4; ++i) {
        int q = q0 + ty * 4 + i;
        if (q < M) {
            float* Sp = S + ((size_t)bh * M + q) * T + t0 + tx * 4;
            #pragma unroll
            for (int j = 0; j < 4; ++j) Sp[j] = acc[i][j] * scale;
        }
    }
}

// ---------------- row softmax (attn1, L=2048) ---------------------------------------
__global__ __launch_bounds__(256) void softmax_rows(float* __restrict__ S, int L)
{
    float* p = S + (size_t)blockIdx.x * L;
    const int tid = threadIdx.x;
    __shared__ float red[256];
    float m = -1e30f;
    for (int i = tid; i < L; i += 256) m = fmaxf(m, p[i]);
    red[tid] = m; __syncthreads();
    for (int s = 128; s; s >>= 1) { if (tid < s) red[tid] = fmaxf(red[tid], red[tid + s]); __syncthreads(); }
    m = red[0]; __syncthreads();
    float sum = 0.f;
    for (int i = tid; i < L; i += 256) { float e = __expf(p[i] - m); p[i] = e; sum += e; }
    red[tid] = sum; __syncthreads();
    for (int s = 128; s; s >>= 1) { if (tid < s) red[tid] += red[tid + s]; __syncthreads(); }
    float inv = 1.f / red[0];
    for (int i = tid; i < L; i += 256) p[i] *= inv;
}

// ====== fused attention for T=64 (attn2/attn3): QK^T -> softmax -> PV -> bf16 ======
__global__ __launch_bounds__(256) void fused_attn64(unsigned short* __restrict__ Ob,
        const float* __restrict__ Q, const float* __restrict__ Kp,
        const float* __restrict__ Vp, int q_bs)
{
    const int bh = blockIdx.y, b = bh >> 4, h = bh & 15;
    const int q0 = blockIdx.x * 64;
    __shared__ float Qs[64][65], Ks[64][65], Vs[64][65];
    __shared__ float ls[64];
    const int tid = threadIdx.x;
    const int lr = tid >> 2, lc = (tid & 3) * 16;
    {
        const float* Qr = Q + ((size_t)q_bs * b + q0 + lr) * DM_ + h * 64 + lc;
        #pragma unroll
        for (int j = 0; j < 16; ++j) Qs[lr][lc + j] = Qr[j];
        const float* Kr = Kp + ((size_t)64 * b + lr) * DM_ + h * 64 + lc;
        #pragma unroll
        for (int j = 0; j < 16; ++j) Ks[lr][lc + j] = Kr[j];
        const float* Vr = Vp + ((size_t)64 * b + lr) * DM_ + h * 64 + lc;
        #pragma unroll
        for (int j = 0; j < 16; ++j) Vs[lr][lc + j] = Vr[j];
    }
    __syncthreads();
    const int ty = tid >> 4, tx = tid & 15;
    float acc[4][4] = {};
    for (int d = 0; d < 64; ++d) {
        float a[4], kk[4];
        #pragma unroll
        for (int i = 0; i < 4; ++i) a[i] = Qs[ty * 4 + i][d];
        #pragma unroll
        for (int j = 0; j < 4; ++j) kk[j] = Ks[tx * 4 + j][d];
        #pragma unroll
        for (int i = 0; i < 4; ++i)
            #pragma unroll
            for (int j = 0; j < 4; ++j) acc[i][j] += a[i] * kk[j];
    }
    float p[4][4]; float lsum[4];
    #pragma unroll
    for (int i = 0; i < 4; ++i) {
        float m = fmaxf(fmaxf(acc[i][0], acc[i][1]), fmaxf(acc[i][2], acc[i][3]));
        #pragma unroll
        for (int o = 1; o <= 8; o <<= 1) m = fmaxf(m, __shfl_xor(m, o, 64));
        float s = 0.f;
        #pragma unroll
        for (int j = 0; j < 4; ++j) { p[i][j] = __expf(acc[i][j] * 0.125f - m * 0.125f); s += p[i][j]; }
        #pragma unroll
        for (int o = 1; o <= 8; o <<= 1) s += __shfl_xor(s, o, 64);
        lsum[i] = s;
    }
    __syncthreads();
    #pragma unroll
    for (int i = 0; i < 4; ++i) {
        #pragma unroll
        for (int j = 0; j < 4; ++j) Qs[ty * 4 + i][tx * 4 + j] = p[i][j];
        if (tx == 0) ls[ty * 4 + i] = lsum[i];
    }
    __syncthreads();
    float O[4][4] = {};
    for (int t = 0; t < 64; ++t) {
        float pp[4], vv[4];
        #pragma unroll
        for (int i = 0; i < 4; ++i) pp[i] = Qs[ty * 4 + i][t];
        #pragma unroll
        for (int j = 0; j < 4; ++j) vv[j] = Vs[t][tx * 4 + j];
        #pragma unroll
        for (int i = 0; i < 4; ++i)
            #pragma unroll
            for (int j = 0; j < 4; ++j) O[i][j] += pp[i] * vv[j];
    }
    #pragma unroll
    for (int i = 0; i < 4; ++i) {
        float inv = 1.f / ls[ty * 4 + i];
        size_t ofs = ((size_t)q_bs * b + q0 + ty * 4 + i) * DM_ + h * 64 + tx * 4;
        #pragma unroll
        for (int j = 0; j < 4; ++j) Ob[ofs + j] = f2bf(O[i][j] * inv);
    }
}

// ---------------- attn1 PV split over T: partial[bh][c][64q][64d] -------------------
__global__ __launch_bounds__(256) void pv_split(float* __restrict__ part,
        const float* __restrict__ P, const float* __restrict__ V)
{
    const int c = blockIdx.x, bh = blockIdx.y, b = bh >> 4, h = bh & 15;
    __shared__ float Ps[64][65], Vs[64][65];
    const int tid = threadIdx.x;
    const int lr = tid >> 2, lc = (tid & 3) * 16;
    const int ty = tid >> 4, tx = tid & 15;
    float acc[4][4] = {};
    for (int it = 0; it < 4; ++it) {
        const int t0 = c * 256 + it * 64;
        const float* Pp = P + ((size_t)bh * 64 + lr) * NT_ + t0 + lc;
        #pragma unroll
        for (int j = 0; j < 16; ++j) Ps[lr][lc + j] = Pp[j];
        const float* Vp = V + ((size_t)NT_ * b + t0 + lr) * DM_ + h * 64 + lc;
        #pragma unroll
        for (int j = 0; j < 16; ++j) Vs[lr][lc + j] = Vp[j];
        __syncthreads();
        for (int t = 0; t < 64; ++t) {
            float pp[4], vv[4];
            #pragma unroll
            for (int i = 0; i < 4; ++i) pp[i] = Ps[ty * 4 + i][t];
            #pragma unroll
            for (int j = 0; j < 4; ++j) vv[j] = Vs[t][tx * 4 + j];
            #pragma unroll
            for (int i = 0; i < 4; ++i)
                #pragma unroll
                for (int j = 0; j < 4; ++j) acc[i][j] += pp[i] * vv[j];
        }
        __syncthreads();
    }
    float* op = part + ((size_t)bh * 8 + c) * 4096;
    #pragma unroll
    for (int i = 0; i < 4; ++i)
        #pragma unroll
        for (int j = 0; j < 4; ++j)
            op[(ty * 4 + i) * 64 + tx * 4 + j] = acc[i][j];
}

__global__ __launch_bounds__(256) void pv_combine(const float* __restrict__ part,
        unsigned short* __restrict__ Zb)
{
    const int bh = blockIdx.x, b = bh >> 4, h = bh & 15;
    for (int idx = threadIdx.x; idx < 4096; idx += 256) {
        int q = idx >> 6, d = idx & 63;
        float s = 0.f;
        #pragma unroll
        for (int c = 0; c < 8; ++c) s += part[((size_t)bh * 8 + c) * 4096 + idx];
        Zb[(size_t)(b * 64 + q) * DM_ + h * 64 + d] = f2bf(s);
    }
}

// ---------------- LayerNorm + add, fp32 + bf16 outputs ------------------------------
__global__ __launch_bounds__(256) void ln_add_dual(const float* __restrict__ X,
        const float* __restrict__ g, const float* __restrict__ bb,
        const float* __restrict__ add, float* __restrict__ out,
        unsigned short* __restrict__ outb)
{
    const int n = blockIdx.x, tid = threadIdx.x;
    const float* x = X + (size_t)n * DM_;
    __shared__ float red[256];
    float v[4]; float s = 0.f;
    #pragma unroll
    for (int i = 0; i < 4; ++i) { v[i] = x[tid + i * 256]; s += v[i]; }
    red[tid] = s; __syncthreads();
    for (int st = 128; st; st >>= 1) { if (tid < st) red[tid] += red[tid + st]; __syncthreads(); }
    float mean = red[0] * (1.f / 1024.f);
    __syncthreads();
    float vs = 0.f;
    #pragma unroll
    for (int i = 0; i < 4; ++i) { float d = v[i] - mean; vs += d * d; }
    red[tid] = vs; __syncthreads();
    for (int st = 128; st; st >>= 1) { if (tid < st) red[tid] += red[tid + st]; __syncthreads(); }
    float inv = 1.f / (sqrtf(red[0] * (1.f / 1023.f)) + 1e-6f);
    #pragma unroll
    for (int i = 0; i < 4; ++i) {
        int d = tid + i * 256;
        float r = g[d] * (v[i] - mean) * inv + bb[d] + add[(size_t)n * DM_ + d];
        out[(size_t)n * DM_ + d] = r;
        outb[(size_t)n * DM_ + d] = f2bf(r);
    }
}

// ---------------- final LN ----------------------------------------------------------
__global__ __launch_bounds__(256) void ln_final(const float* __restrict__ X,
        const float* __restrict__ g, const float* __restrict__ bb,
        const float* __restrict__ t, const float* __restrict__ lb,
        float* __restrict__ out)
{
    const int n = blockIdx.x, tid = threadIdx.x;
    const float* x = X + (size_t)n * DM_;
    __shared__ float red[256];
    float v[4]; float s = 0.f;
    #pragma unroll
    for (int i = 0; i < 4; ++i) { v[i] = x[tid + i * 256]; s += v[i]; }
    red[tid] = s; __syncthreads();
    for (int st = 128; st; st >>= 1) { if (tid < st) red[tid] += red[tid + st]; __syncthreads(); }
    float mean = red[0] * (1.f / 1024.f);
    __syncthreads();
    float vs = 0.f;
    #pragma unroll
    for (int i = 0; i < 4; ++i) { float d = v[i] - mean; vs += d * d; }
    red[tid] = vs; __syncthreads();
    for (int st = 128; st; st >>= 1) { if (tid < st) red[tid] += red[tid + st]; __syncthreads(); }
    float inv = 1.f / (sqrtf(red[0] * (1.f / 1023.f)) + 1e-6f);
    #pragma unroll
    for (int i = 0; i < 4; ++i) {
        int d = tid + i * 256;
        out[(size_t)n * DM_ + d] = g[d] * (v[i] - mean) * inv + bb[d]
                                 + t[(size_t)n * DM_ + d] + lb[d];
    }
}

// ---------------- router ------------------------------------------------------------
__global__ __launch_bounds__(256) void router_kernel(const float* __restrict__ X1,
        const float* __restrict__ Wr, const float* __restrict__ br,
        int* __restrict__ topi, float* __restrict__ gates, int* __restrict__ counts)
{
    const int n = blockIdx.x, tid = threadIdx.x;
    const int e = tid >> 5, l = tid & 31;
    const float* x = X1 + (size_t)n * DM_;
    float s = 0.f;
    for (int k = l; k < DM_; k += 32) s += x[k] * Wr[k * NEXP_ + e];
    for (int off = 16; off; off >>= 1) s += __shfl_down(s, off, 32);
    __shared__ float lg[NEXP_];
    if (l == 0) lg[e] = s + br[e];
    __syncthreads();
    if (tid == 0) {
        float v1 = -1e30f; int i1 = 0;
        for (int ee = 0; ee < NEXP_; ++ee) if (lg[ee] > v1) { v1 = lg[ee]; i1 = ee; }
        float v2 = -1e30f; int i2 = 0;
        for (int ee = 0; ee < NEXP_; ++ee) if (ee != i1 && lg[ee] > v2) { v2 = lg[ee]; i2 = ee; }
        float e2 = __expf(v2 - v1);
        float inv = 1.f / (1.f + e2);
        topi[n * 2] = i1; topi[n * 2 + 1] = i2;
        gates[n * 2] = inv; gates[n * 2 + 1] = e2 * inv;
        atomicAdd(&counts[i1], 1); atomicAdd(&counts[i2], 1);
    }
}

__global__ void zero_counts(int* __restrict__ counts)
{
    if (threadIdx.x < NEXP_) counts[threadIdx.x] = 0;
}

__global__ void router_offsets(const int* __restrict__ counts, int* __restrict__ offs,
                               int* __restrict__ fill)
{
    if (threadIdx.x == 0) {
        int acc = 0;
        for (int e = 0; e < NEXP_; ++e) { offs[e] = acc; acc += counts[e]; fill[e] = 0; }
    }
}

__global__ __launch_bounds__(256) void router_scatter(const int* __restrict__ topi,
        int* __restrict__ fill, const int* __restrict__ offs,
        int* __restrict__ ptok, int* __restrict__ pidx)
{
    int n = blockIdx.x * 256 + threadIdx.x;
    if (n >= NTOK_) return;
    #pragma unroll
    for (int s2 = 0; s2 < 2; ++s2) {
        int e = topi[n * 2 + s2];
        int r = atomicAdd(&fill[e], 1);
        int p = offs[e] + r;
        ptok[p] = n;
        pidx[n * 2 + s2] = p;
    }
}

// ============== MoE up (dual GEMM + silu-glu), 128x64 tile, reg prefetch ===========
__global__ __launch_bounds__(256) void moe_up_mfma(
        const unsigned short* __restrict__ X1b,
        const unsigned short* __restrict__ WTa, const unsigned short* __restrict__ VTa,
        unsigned short* __restrict__ H,
        const int* __restrict__ cnt, const int* __restrict__ offs,
        const int* __restrict__ ptok)
{
    const int e = blockIdx.z;
    const int ce = cnt[e];
    const int m0 = blockIdx.y * 128;
    if (m0 >= ce) return;
    const int n0 = blockIdx.x * 64;
    const int base = offs[e];
    const unsigned short* WT = WTa + (size_t)e * DHID_ * DM_;
    const unsigned short* VT = VTa + (size_t)e * DHID_ * DM_;
    __shared__ unsigned short As[128 * 64];
    __shared__ unsigned short Ws[64 * 64];
    __shared__ unsigned short Vs[64 * 64];
    __shared__ int rtok[128];
    const int tid = threadIdx.x;
    const int wid = tid >> 6, lane = tid & 63;
    if (tid < 128) {
        int r = m0 + tid;
        rtok[tid] = (r < ce) ? ptok[base + r] : ptok[base + ce - 1];
    }
    __syncthreads();

    const unsigned short* aSrc[4]; int aWr[4];
    #pragma unroll
    for (int i = 0; i < 4; ++i) {
        int idx = tid + 256 * i;
        int row = idx >> 3, c8 = idx & 7;
        aSrc[i] = X1b + (size_t)rtok[row] * DM_ + c8 * 8;
        aWr[i] = (row * 128 + c8 * 16) ^ ((row & 7) << 4);
    }
    const unsigned short* wSrc[2]; const unsigned short* vSrc[2]; int bWr[2];
    #pragma unroll
    for (int i = 0; i < 2; ++i) {
        int idx = tid + 256 * i;
        int row = idx >> 3, c8 = idx & 7;
        wSrc[i] = WT + (size_t)(n0 + row) * DM_ + c8 * 8;
        vSrc[i] = VT + (size_t)(n0 + row) * DM_ + c8 * 8;
        bWr[i] = (row * 128 + c8 * 16) ^ ((row & 7) << 4);
    }
    const int wr = wid >> 1, wc = wid & 1;
    int ra[2][4], rb[2][2];
    #pragma unroll
    for (int kk = 0; kk < 2; ++kk) {
        #pragma unroll
        for (int t = 0; t < 4; ++t) {
            int rowa = wr * 64 + t * 16 + (lane & 15);
            int kb = kk * 64 + (lane >> 4) * 16;
            ra[kk][t] = (rowa * 128 + kb) ^ ((rowa & 7) << 4);
        }
        #pragma unroll
        for (int t = 0; t < 2; ++t) {
            int rowb = wc * 32 + t * 16 + (lane & 15);
            int kb = kk * 64 + (lane >> 4) * 16;
            rb[kk][t] = (rowb * 128 + kb) ^ ((rowb & 7) << 4);
        }
    }
    const f32x4 zero = {0.f, 0.f, 0.f, 0.f};
    f32x4 accw[4][2], accv[4][2];
    #pragma unroll
    for (int i = 0; i < 4; ++i)
        #pragma unroll
        for (int j = 0; j < 2; ++j) { accw[i][j] = zero; accv[i][j] = zero; }

    short8 sa[4], sw[2], sv[2];
    #pragma unroll
    for (int i = 0; i < 4; ++i) sa[i] = *(const short8*)(aSrc[i]);
    #pragma unroll
    for (int i = 0; i < 2; ++i) { sw[i] = *(const short8*)(wSrc[i]); sv[i] = *(const short8*)(vSrc[i]); }
    const int nk = DM_ >> 6;
    for (int kt = 0; kt < nk; ++kt) {
        #pragma unroll
        for (int i = 0; i < 4; ++i) *(short8*)((char*)As + aWr[i]) = sa[i];
        #pragma unroll
        for (int i = 0; i < 2; ++i) {
            *(short8*)((char*)Ws + bWr[i]) = sw[i];
            *(short8*)((char*)Vs + bWr[i]) = sv[i];
        }
        __syncthreads();
        if (kt + 1 < nk) {
            int ko = (kt + 1) << 6;
            #pragma unroll
            for (int i = 0; i < 4; ++i) sa[i] = *(const short8*)(aSrc[i] + ko);
            #pragma unroll
            for (int i = 0; i < 2; ++i) { sw[i] = *(const short8*)(wSrc[i] + ko); sv[i] = *(const short8*)(vSrc[i] + ko); }
        }
        #pragma unroll
        for (int kk = 0; kk < 2; ++kk) {
            short8 af[4], bw[2], bv[2];
            #pragma unroll
            for (int t = 0; t < 4; ++t) af[t] = *(const short8*)((const char*)As + ra[kk][t]);
            #pragma unroll
            for (int t = 0; t < 2; ++t) {
                bw[t] = *(const short8*)((const char*)Ws + rb[kk][t]);
                bv[t] = *(const short8*)((const char*)Vs + rb[kk][t]);
            }
            #pragma unroll
            for (int i = 0; i < 4; ++i)
                #pragma unroll
                for (int j = 0; j < 2; ++j) {
                    accw[i][j] = __builtin_amdgcn_mfma_f32_16x16x32_bf16(af[i], bw[j], accw[i][j], 0, 0, 0);
                    accv[i][j] = __builtin_amdgcn_mfma_f32_16x16x32_bf16(af[i], bv[j], accv[i][j], 0, 0, 0);
                }
        }
        __syncthreads();
    }
    const int cl = lane & 15, g4 = lane >> 4;
    #pragma unroll
    for (int i = 0; i < 4; ++i)
        #pragma unroll
        for (int j = 0; j < 2; ++j)
            #pragma unroll
            for (int r = 0; r < 4; ++r) {
                int rl = m0 + wr * 64 + i * 16 + g4 * 4 + r;
                if (rl < ce) {
                    float a = accw[i][j][r], b = accv[i][j][r];
                    float h = a * (b / (1.f + __expf(-b)));
                    H[(size_t)(base + rl) * DHID_ + n0 + wc * 32 + j * 16 + cl] = f2bf(h);
                }
            }
}

// ============== MoE down: PY f32 = H bf16 @ WoT^T, 128x128, prefetch ===============
__global__ __launch_bounds__(256) void moe_down_mfma(
        const unsigned short* __restrict__ H, const unsigned short* __restrict__ WoTa,
        float* __restrict__ PY,
        const int* __restrict__ cnt, const int* __restrict__ offs)
{
    const int e = blockIdx.z;
    const int ce = cnt[e];
    const int m0 = blockIdx.y * 128;
    if (m0 >= ce) return;
    const int n0 = blockIdx.x * 128;
    const int base = offs[e];
    const unsigned short* WoT = WoTa + (size_t)e * DM_ * DHID_;
    __shared__ unsigned short As[128 * 64];
    __shared__ unsigned short Bs[128 * 64];
    const int tid = threadIdx.x;
    const int wid = tid >> 6, lane = tid & 63;

    const unsigned short* aSrc[4]; const unsigned short* bSrc[4]; int sWr[4];
    #pragma unroll
    for (int i = 0; i < 4; ++i) {
        int idx = tid + 256 * i;
        int row = idx >> 3, c8 = idx & 7;
        int r = m0 + row; if (r >= ce) r = ce - 1;
        aSrc[i] = H + (size_t)(base + r) * DHID_ + c8 * 8;
        bSrc[i] = WoT + (size_t)(n0 + row) * DHID_ + c8 * 8;
        sWr[i] = (row * 128 + c8 * 16) ^ ((row & 7) << 4);
    }
    const int wr = wid >> 1, wc = wid & 1;
    int ra[2][4], rb[2][4];
    #pragma unroll
    for (int kk = 0; kk < 2; ++kk) {
        #pragma unroll
        for (int t = 0; t < 4; ++t) {
            int kb = kk * 64 + (lane >> 4) * 16;
            int rowa = wr * 64 + t * 16 + (lane & 15);
            ra[kk][t] = (rowa * 128 + kb) ^ ((rowa & 7) << 4);
            int rowb = wc * 64 + t * 16 + (lane & 15);
            rb[kk][t] = (rowb * 128 + kb) ^ ((rowb & 7) << 4);
        }
    }
    const f32x4 zero = {0.f, 0.f, 0.f, 0.f};
    f32x4 acc[4][4];
    #pragma unroll
    for (int i = 0; i < 4; ++i)
        #pragma unroll
        for (int j = 0; j < 4; ++j) acc[i][j] = zero;

    short8 sa[4], sb[4];
    #pragma unroll
    for (int i = 0; i < 4; ++i) { sa[i] = *(const short8*)(aSrc[i]); sb[i] = *(const short8*)(bSrc[i]); }
    const int nk = DHID_ >> 6;
    for (int kt = 0; kt < nk; ++kt) {
        #pragma unroll
        for (int i = 0; i < 4; ++i) {
            *(short8*)((char*)As + sWr[i]) = sa[i];
            *(short8*)((char*)Bs + sWr[i]) = sb[i];
        }
        __syncthreads();
        if (kt + 1 < nk) {
            int ko = (kt + 1) << 6;
            #pragma unroll
            for (int i = 0; i < 4; ++i) { sa[i] = *(const short8*)(aSrc[i] + ko); sb[i] = *(const short8*)(bSrc[i] + ko); }
        }
        #pragma unroll
        for (int kk = 0; kk < 2; ++kk) {
            short8 af[4], bfr[4];
            #pragma unroll
            for (int t = 0; t < 4; ++t) {
                af[t]  = *(const short8*)((const char*)As + ra[kk][t]);
                bfr[t] = *(const short8*)((const char*)Bs + rb[kk][t]);
            }
            #pragma unroll
            for (int i = 0; i < 4; ++i)
                #pragma unroll
                for (int j = 0; j < 4; ++j)
                    acc[i][j] = __builtin_amdgcn_mfma_f32_16x16x32_bf16(af[i], bfr[j], acc[i][j], 0, 0, 0);
        }
        __syncthreads();
    }
    const int cl = lane & 15, g4 = lane >> 4;
    #pragma unroll
    for (int i = 0; i < 4; ++i)
        #pragma unroll
        for (int j = 0; j < 4; ++j)
            #pragma unroll
            for (int r = 0; r < 4; ++r) {
                int rl = m0 + wr * 64 + i * 16 + g4 * 4 + r;
                if (rl < ce)
                    PY[(size_t)(base + rl) * DM_ + n0 + wc * 64 + j * 16 + cl] = acc[i][j][r];
            }
}

// ---------------- combine -----------------------------------------------------------
__global__ __launch_bounds__(256) void moe_combine(const float* __restrict__ PY,
        const int* __restrict__ pidx, const float* __restrict__ gates,
        float* __restrict__ MO)
{
    int n = blockIdx.x, tid = threadIdx.x;
    int p0 = pidx[n * 2], p1 = pidx[n * 2 + 1];
    float g0 = gates[n * 2], g1 = gates[n * 2 + 1];
    #pragma unroll
    for (int i = 0; i < 4; ++i) {
        int d = tid + i * 256;
        MO[(size_t)n * DM_ + d] = g0 * PY[(size_t)p0 * DM_ + d] + g1 * PY[(size_t)p1 * DM_ + d];
    }
}

extern "C" void kernel_launch(void* const* d_in, const int* in_sizes, int n_in,
                              void* d_out, int out_size, void* d_ws, size_t ws_size,
                              hipStream_t stream)
{
    const float* x      = (const float*)d_in[0];
    const float* cosb   = (const float*)d_in[1];
    const float* sinb   = (const float*)d_in[2];
    const float* ln1g   = (const float*)d_in[3];
    const float* ln1b   = (const float*)d_in[4];
    const float* ln2g   = (const float*)d_in[5];
    const float* ln2b   = (const float*)d_in[6];
    const float* ln3g   = (const float*)d_in[7];
    const float* ln3b   = (const float*)d_in[8];
    const float* Lat    = (const float*)d_in[9];
    const float* Wq_lat = (const float*)d_in[10];
    const float* Wk_in  = (const float*)d_in[11];
    const float* Wv_in  = (const float*)d_in[12];
    const float* Wq_in  = (const float*)d_in[13];
    const float* Wk_lat = (const float*)d_in[14];
    const float* Wv_lat = (const float*)d_in[15];
    const float* Wout   = (const float*)d_in[16];
    const float* rW     = (const float*)d_in[17];
    const float* rb     = (const float*)d_in[18];
    const float* eW     = (const float*)d_in[19];
    const float* eV     = (const float*)d_in[20];
    const float* eWo    = (const float*)d_in[21];
    const float* linW   = (const float*)d_in[22];
    const float* linb   = (const float*)d_in[23];
    float* out = (float*)d_out;

    float* ws = (float*)d_ws;
    const size_t M1 = 1024 * 1024;
    float* buf0 = ws;                 // K-proj / MoE out
    float* buf1 = ws + 4 * M1;        // V-proj / attn out / X2
    float* buf2 = ws + 8 * M1;        // Q-proj(rope) / X1
    float* buf3 = ws + 12 * M1;       // S1 / final-linear out
    size_t off = 16 * M1;
    float* qlat = ws + off; off += 65536;
    float* qlb  = ws + off; off += 131072;
    float* klb  = ws + off; off += 131072;
    float* vlb  = ws + off; off += 131072;
    float* s2b  = ws + off; off += 131072;
    float* z2b  = ws + off; off += 131072;
    float* kzb  = ws + off; off += 131072;
    float* vzb  = ws + off; off += 131072;
    float* gates = ws + off; off += 8192;
    int* iarea = (int*)(ws + off); off += 32768;
    int* topi   = iarea;
    int* counts = iarea + 8192;
    int* offs   = iarea + 8200;
    int* fill   = iarea + 8208;
    int* ptok   = iarea + 8216;
    int* pidx   = iarea + 16408;
    unsigned short* zb_b  = (unsigned short*)(ws + off); off += 65536;
    unsigned short* z2b_b = (unsigned short*)(ws + off); off += 65536;
    unsigned short* latb  = (unsigned short*)(ws + off); off += 32768;
    unsigned short* x1b   = (unsigned short*)(ws + off); off += 2 * M1;
    unsigned short* WkT   = (unsigned short*)(ws + off); off += 3 * (M1 / 2);
    unsigned short* WoutT = (unsigned short*)(ws + off); off += M1 / 2;   // + linWT contiguous
    unsigned short* linWT = (unsigned short*)(ws + off); off += M1 / 2;
    unsigned short* WlatT = (unsigned short*)(ws + off); off += 3 * (M1 / 2);

    unsigned short* Hbuf  = (unsigned short*)(ws + 24 * M1);
    unsigned short* actb  = (unsigned short*)(ws + 24 * M1);   // alias
    unsigned short* x2b   = (unsigned short*)(ws + 24 * M1);   // alias
    float* pvpart         = ws + 26 * M1;
    unsigned short* eWT   = (unsigned short*)(ws + 40 * M1);   // eWT..eVT contiguous 32MB+32MB
    unsigned short* eVT   = (unsigned short*)(ws + 56 * M1);
    unsigned short* eWoT  = eWT;
    float* PY             = ws + 56 * M1;

    dim3 blk(256);

    zero_counts<<<1, 64, 0, stream>>>(counts);

    // weight prep
    tconv3<<<dim3(16, 16, 3), blk, 0, stream>>>(Wk_in, Wv_in, Wq_in, WkT);
    tconv3<<<dim3(16, 16, 2), blk, 0, stream>>>(Wout, linW, linW, WoutT);   // z=0,1 only
    tconv3<<<dim3(16, 16, 3), blk, 0, stream>>>(Wq_lat, Wk_lat, Wv_lat, WlatT);
    tconvEV<<<dim3(64, 16, 16), blk, 0, stream>>>(eW, eV, eWT);
    c2b<<<2048, blk, 0, stream>>>(x, actb, 524288);
    c2b<<<32, blk, 0, stream>>>(Lat, latb, 8192);

    // qlat = Lat @ Wq_lat
    gemm_lat<<<dim3(16, 1), blk, 0, stream>>>(latb, WlatT, (int)M1, qlat, 0, 64);

    // projections (K rope z=0, V plain z=1, Q rope z=2)
    gemm_proj3<<<dim3(8, 32, 3), blk, 0, stream>>>(actb, WkT, buf0, cosb, sinb);

    // attn1: latents query tokens
    attn_scores<<<dim3(32, 1, 32), blk, 0, stream>>>(buf3, qlat, buf0, 64, 2048, 0, 2048, 0.125f);
    softmax_rows<<<2048, blk, 0, stream>>>(buf3, 2048);
    pv_split<<<dim3(8, 32), blk, 0, stream>>>(pvpart, buf3, buf1);
    pv_combine<<<32, blk, 0, stream>>>(pvpart, zb_b);

    // attn2: latents self-attention (fused)
    gemm_lat<<<dim3(16, 3), blk, 0, stream>>>(zb_b, WlatT, (int)M1, qlb, 131072, 128);
    fused_attn64<<<dim3(1, 32), blk, 0, stream>>>(z2b_b, qlb, klb, vlb, 64);

    // attn3: tokens query latents (fused)
    gemm_lat<<<dim3(16, 2), blk, 0, stream>>>(z2b_b, WlatT + M1, (int)M1, kzb, 131072, 128);
    fused_attn64<<<dim3(32, 32), blk, 0, stream>>>(actb, buf2, kzb, vzb, 2048);
    gemm_bf16_128<<<dim3(8, 32), blk, 0, stream>>>(actb, WoutT, buf1, 4096, 1024, 1024);

    // residual 1: X1 = LN1(x) + attn
    ln_add_dual<<<4096, blk, 0, stream>>>(x, ln1g, ln1b, buf1, buf2, x1b);

    // MoE
    router_kernel<<<4096, blk, 0, stream>>>(buf2, rW, rb, topi, gates, counts);
    router_offsets<<<1, 64, 0, stream>>>(counts, offs, fill);
    router_scatter<<<16, blk, 0, stream>>>(topi, fill, offs, ptok, pidx);
    moe_up_mfma<<<dim3(64, 32, 8), blk, 0, stream>>>(x1b, eWT, eVT, Hbuf, counts, offs, ptok);
    tconv<<<dim3(16, 64, 8), blk, 0, stream>>>(eWo, eWoT, 4096, 1024);
    moe_down_mfma<<<dim3(8, 32, 8), blk, 0, stream>>>(Hbuf, eWoT, PY, counts, offs);
    moe_combine<<<4096, blk, 0, stream>>>(PY, pidx, gates, buf0);

    // residual 2: X2 = LN2(X1) + MoE
    ln_add_dual<<<4096, blk, 0, stream>>>(buf2, ln2g, ln2b, buf0, buf1, x2b);

    // final linear + residual 3
    gemm_bf16_128<<<dim3(8, 32), blk, 0, stream>>>(x2b, linWT, buf3, 4096, 1024, 1024);
    ln_final<<<4096, blk, 0, stream>>>(buf1, ln3g, ln3b, buf3, linb, out);
}

// Round 12
// 982.707 us; speedup vs baseline: 1.1199x; 1.0109x over previous
//
#include <hip/hip_runtime.h>
#include <hip/hip_bf16.h>
#include <math.h>

typedef __hip_bfloat16 bf16;
typedef __attribute__((ext_vector_type(8))) short short8;
typedef __attribute__((ext_vector_type(8))) unsigned short ushort8;
typedef __attribute__((ext_vector_type(4))) float f32x4;

#define NT_   2048
#define NTOK_ 4096
#define DM_   1024
#define DHID_ 4096
#define NEXP_ 8

__device__ __forceinline__ unsigned short f2bf(float f) {
    unsigned u = __float_as_uint(f);
    u = u + 0x7FFF + ((u >> 16) & 1);
    return (unsigned short)(u >> 16);
}
__device__ __forceinline__ float bf2f(unsigned short u) {
    return __uint_as_float((unsigned)u << 16);
}

// ============================ fp32 -> bf16 convert (flat) ==========================
__global__ __launch_bounds__(256) void c2b(const float* __restrict__ in,
        unsigned short* __restrict__ out, int n8)
{
    int i = blockIdx.x * 256 + threadIdx.x;
    if (i >= n8) return;
    const float4 v0 = *(const float4*)(in + (size_t)i * 8);
    const float4 v1 = *(const float4*)(in + (size_t)i * 8 + 4);
    ushort8 o;
    o[0] = f2bf(v0.x); o[1] = f2bf(v0.y); o[2] = f2bf(v0.z); o[3] = f2bf(v0.w);
    o[4] = f2bf(v1.x); o[5] = f2bf(v1.y); o[6] = f2bf(v1.z); o[7] = f2bf(v1.w);
    *(ushort8*)(out + (size_t)i * 8) = o;
}

// ================== transpose+convert: in f32 [R][C] -> out bf16 [C][R] ============
__global__ __launch_bounds__(256) void tconv(const float* __restrict__ in,
        unsigned short* __restrict__ out, int R, int C)
{
    __shared__ float t[64][65];
    const size_t mofs = (size_t)blockIdx.z * R * C;
    const int r0 = blockIdx.y * 64, c0 = blockIdx.x * 64;
    const int tid = threadIdx.x;
    const int lr = tid >> 4, lc4 = (tid & 15) * 4;
    #pragma unroll
    for (int i = 0; i < 4; ++i) {
        float4 v = *(const float4*)(in + mofs + (size_t)(r0 + lr + i * 16) * C + c0 + lc4);
        t[lr + i * 16][lc4 + 0] = v.x; t[lr + i * 16][lc4 + 1] = v.y;
        t[lr + i * 16][lc4 + 2] = v.z; t[lr + i * 16][lc4 + 3] = v.w;
    }
    __syncthreads();
    const int oc = tid >> 2;
    const int j0 = (tid & 3) * 16;
    ushort8 o0, o1;
    #pragma unroll
    for (int j = 0; j < 8; ++j)  o0[j] = f2bf(t[j0 + j][oc]);
    #pragma unroll
    for (int j = 0; j < 8; ++j)  o1[j] = f2bf(t[j0 + 8 + j][oc]);
    size_t ob = mofs + (size_t)(c0 + oc) * R + r0 + j0;
    *(ushort8*)(out + ob) = o0;
    *(ushort8*)(out + ob + 8) = o1;
}

// three separate sources (batched over z), same R=C=1024
__global__ __launch_bounds__(256) void tconv3(const float* __restrict__ s0,
        const float* __restrict__ s1, const float* __restrict__ s2,
        unsigned short* __restrict__ out)
{
    __shared__ float t[64][65];
    const float* in = blockIdx.z == 0 ? s0 : (blockIdx.z == 1 ? s1 : s2);
    unsigned short* o = out + (size_t)blockIdx.z * DM_ * DM_;
    const int r0 = blockIdx.y * 64, c0 = blockIdx.x * 64;
    const int tid = threadIdx.x;
    const int lr = tid >> 4, lc4 = (tid & 15) * 4;
    #pragma unroll
    for (int i = 0; i < 4; ++i) {
        float4 v = *(const float4*)(in + (size_t)(r0 + lr + i * 16) * DM_ + c0 + lc4);
        t[lr + i * 16][lc4 + 0] = v.x; t[lr + i * 16][lc4 + 1] = v.y;
        t[lr + i * 16][lc4 + 2] = v.z; t[lr + i * 16][lc4 + 3] = v.w;
    }
    __syncthreads();
    const int oc = tid >> 2;
    const int j0 = (tid & 3) * 16;
    ushort8 o0, o1;
    #pragma unroll
    for (int j = 0; j < 8; ++j)  o0[j] = f2bf(t[j0 + j][oc]);
    #pragma unroll
    for (int j = 0; j < 8; ++j)  o1[j] = f2bf(t[j0 + 8 + j][oc]);
    size_t ob = (size_t)(c0 + oc) * DM_ + r0 + j0;
    *(ushort8*)(o + ob) = o0;
    *(ushort8*)(o + ob + 8) = o1;
}

// ====== eW+eV transpose in one launch: z<8 -> eW[z], else eV[z-8]; R=1024 C=4096 ====
__global__ __launch_bounds__(256) void tconvEV(const float* __restrict__ s0,
        const float* __restrict__ s1, unsigned short* __restrict__ out)
{
    __shared__ float t[64][65];
    const int z = blockIdx.z;
    const size_t rc = (size_t)DM_ * DHID_;
    const float* in = (z < 8) ? (s0 + (size_t)z * rc) : (s1 + (size_t)(z - 8) * rc);
    unsigned short* o = out + (size_t)z * rc;
    const int r0 = blockIdx.y * 64, c0 = blockIdx.x * 64;
    const int tid = threadIdx.x;
    const int lr = tid >> 4, lc4 = (tid & 15) * 4;
    #pragma unroll
    for (int i = 0; i < 4; ++i) {
        float4 v = *(const float4*)(in + (size_t)(r0 + lr + i * 16) * DHID_ + c0 + lc4);
        t[lr + i * 16][lc4 + 0] = v.x; t[lr + i * 16][lc4 + 1] = v.y;
        t[lr + i * 16][lc4 + 2] = v.z; t[lr + i * 16][lc4 + 3] = v.w;
    }
    __syncthreads();
    const int oc = tid >> 2;
    const int j0 = (tid & 3) * 16;
    ushort8 o0, o1;
    #pragma unroll
    for (int j = 0; j < 8; ++j)  o0[j] = f2bf(t[j0 + j][oc]);
    #pragma unroll
    for (int j = 0; j < 8; ++j)  o1[j] = f2bf(t[j0 + 8 + j][oc]);
    size_t ob = (size_t)(c0 + oc) * DM_ + r0 + j0;
    *(ushort8*)(o + ob) = o0;
    *(ushort8*)(o + ob + 8) = o1;
}

// =========== MFMA GEMM: C f32[M,N] = A bf16[M,K] @ (BT bf16[N,K])^T ================
__global__ __launch_bounds__(256) void gemm_bf16_128(
        const unsigned short* __restrict__ A, const unsigned short* __restrict__ BT,
        float* __restrict__ C, int M, int N, int K)
{
    __shared__ unsigned short As[128 * 64];
    __shared__ unsigned short Bs[128 * 64];
    const int tid = threadIdx.x;
    const int wid = tid >> 6, lane = tid & 63;
    const int m0 = blockIdx.y * 128, n0 = blockIdx.x * 128;

    const unsigned short* aSrc[4]; const unsigned short* bSrc[4]; int sWr[4];
    #pragma unroll
    for (int i = 0; i < 4; ++i) {
        int idx = tid + 256 * i;
        int row = idx >> 3, c8 = idx & 7;
        int ar = m0 + row; if (ar >= M) ar = M - 1;
        aSrc[i] = A + (size_t)ar * K + c8 * 8;
        bSrc[i] = BT + (size_t)(n0 + row) * K + c8 * 8;
        sWr[i] = (row * 128 + c8 * 16) ^ ((row & 7) << 4);
    }
    const int wr = wid >> 1, wc = wid & 1;
    int ra[2][4], rb[2][4];
    #pragma unroll
    for (int kk = 0; kk < 2; ++kk) {
        #pragma unroll
        for (int t = 0; t < 4; ++t) {
            int kb = kk * 64 + (lane >> 4) * 16;
            int rowa = wr * 64 + t * 16 + (lane & 15);
            ra[kk][t] = (rowa * 128 + kb) ^ ((rowa & 7) << 4);
            int rowb = wc * 64 + t * 16 + (lane & 15);
            rb[kk][t] = (rowb * 128 + kb) ^ ((rowb & 7) << 4);
        }
    }
    const f32x4 zero = {0.f, 0.f, 0.f, 0.f};
    f32x4 acc[4][4];
    #pragma unroll
    for (int i = 0; i < 4; ++i)
        #pragma unroll
        for (int j = 0; j < 4; ++j) acc[i][j] = zero;

    short8 sa[4], sb[4];
    #pragma unroll
    for (int i = 0; i < 4; ++i) { sa[i] = *(const short8*)(aSrc[i]); sb[i] = *(const short8*)(bSrc[i]); }
    const int nk = K >> 6;
    for (int kt = 0; kt < nk; ++kt) {
        #pragma unroll
        for (int i = 0; i < 4; ++i) {
            *(short8*)((char*)As + sWr[i]) = sa[i];
            *(short8*)((char*)Bs + sWr[i]) = sb[i];
        }
        __syncthreads();
        if (kt + 1 < nk) {
            int ko = (kt + 1) << 6;
            #pragma unroll
            for (int i = 0; i < 4; ++i) { sa[i] = *(const short8*)(aSrc[i] + ko); sb[i] = *(const short8*)(bSrc[i] + ko); }
        }
        #pragma unroll
        for (int kk = 0; kk < 2; ++kk) {
            short8 af[4], bfr[4];
            #pragma unroll
            for (int t = 0; t < 4; ++t) {
                af[t]  = *(const short8*)((const char*)As + ra[kk][t]);
                bfr[t] = *(const short8*)((const char*)Bs + rb[kk][t]);
            }
            #pragma unroll
            for (int i = 0; i < 4; ++i)
                #pragma unroll
                for (int j = 0; j < 4; ++j)
                    acc[i][j] = __builtin_amdgcn_mfma_f32_16x16x32_bf16(af[i], bfr[j], acc[i][j], 0, 0, 0);
        }
        __syncthreads();
    }
    const int cl = lane & 15, g4 = lane >> 4;
    #pragma unroll
    for (int i = 0; i < 4; ++i)
        #pragma unroll
        for (int j = 0; j < 4; ++j)
            #pragma unroll
            for (int r = 0; r < 4; ++r) {
                int rr = m0 + wr * 64 + i * 16 + g4 * 4 + r;
                if (rr < M) C[(size_t)rr * N + n0 + wc * 64 + j * 16 + cl] = acc[i][j][r];
            }
}

// ====== batched projections x@{Wk,Wv,Wq} with fused RoPE on z=0 (K) and z=2 (Q) ====
__global__ __launch_bounds__(256) void gemm_proj3(
        const unsigned short* __restrict__ A, const unsigned short* __restrict__ BT0,
        float* __restrict__ C0, const float* __restrict__ cosb,
        const float* __restrict__ sinb)
{
    const int z = blockIdx.z;
    const unsigned short* BT = BT0 + (size_t)z * DM_ * DM_;
    float* C = C0 + (size_t)z * NTOK_ * DM_;
    const bool doRope = (z != 1);
    __shared__ unsigned short As[128 * 64];
    __shared__ unsigned short Bs[128 * 64];
    const int tid = threadIdx.x;
    const int wid = tid >> 6, lane = tid & 63;
    const int m0 = blockIdx.y * 128, n0 = blockIdx.x * 128;
    const int K = DM_, N = DM_;

    const unsigned short* aSrc[4]; const unsigned short* bSrc[4]; int sWr[4];
    #pragma unroll
    for (int i = 0; i < 4; ++i) {
        int idx = tid + 256 * i;
        int row = idx >> 3, c8 = idx & 7;
        aSrc[i] = A + (size_t)(m0 + row) * K + c8 * 8;
        bSrc[i] = BT + (size_t)(n0 + row) * K + c8 * 8;
        sWr[i] = (row * 128 + c8 * 16) ^ ((row & 7) << 4);
    }
    const int wr = wid >> 1, wc = wid & 1;
    int ra[2][4], rb[2][4];
    #pragma unroll
    for (int kk = 0; kk < 2; ++kk) {
        #pragma unroll
        for (int t = 0; t < 4; ++t) {
            int kb = kk * 64 + (lane >> 4) * 16;
            int rowa = wr * 64 + t * 16 + (lane & 15);
            ra[kk][t] = (rowa * 128 + kb) ^ ((rowa & 7) << 4);
            int rowb = wc * 64 + t * 16 + (lane & 15);
            rb[kk][t] = (rowb * 128 + kb) ^ ((rowb & 7) << 4);
        }
    }
    const f32x4 zero = {0.f, 0.f, 0.f, 0.f};
    f32x4 acc[4][4];
    #pragma unroll
    for (int i = 0; i < 4; ++i)
        #pragma unroll
        for (int j = 0; j < 4; ++j) acc[i][j] = zero;

    short8 sa[4], sb[4];
    #pragma unroll
    for (int i = 0; i < 4; ++i) { sa[i] = *(const short8*)(aSrc[i]); sb[i] = *(const short8*)(bSrc[i]); }
    const int nk = K >> 6;
    for (int kt = 0; kt < nk; ++kt) {
        #pragma unroll
        for (int i = 0; i < 4; ++i) {
            *(short8*)((char*)As + sWr[i]) = sa[i];
            *(short8*)((char*)Bs + sWr[i]) = sb[i];
        }
        __syncthreads();
        if (kt + 1 < nk) {
            int ko = (kt + 1) << 6;
            #pragma unroll
            for (int i = 0; i < 4; ++i) { sa[i] = *(const short8*)(aSrc[i] + ko); sb[i] = *(const short8*)(bSrc[i] + ko); }
        }
        #pragma unroll
        for (int kk = 0; kk < 2; ++kk) {
            short8 af[4], bfr[4];
            #pragma unroll
            for (int t = 0; t < 4; ++t) {
                af[t]  = *(const short8*)((const char*)As + ra[kk][t]);
                bfr[t] = *(const short8*)((const char*)Bs + rb[kk][t]);
            }
            #pragma unroll
            for (int i = 0; i < 4; ++i)
                #pragma unroll
                for (int j = 0; j < 4; ++j)
                    acc[i][j] = __builtin_amdgcn_mfma_f32_16x16x32_bf16(af[i], bfr[j], acc[i][j], 0, 0, 0);
        }
        __syncthreads();
    }
    const int cl = lane & 15, g4 = lane >> 4;
    #pragma unroll
    for (int i = 0; i < 4; ++i)
        #pragma unroll
        for (int j = 0; j < 4; ++j) {
            const int cc = n0 + wc * 64 + j * 16 + cl;
            const int ii = (cc & 63) >> 1;
            const bool even = (cc & 1) == 0;
            #pragma unroll
            for (int r = 0; r < 4; ++r) {
                const int rr = m0 + wr * 64 + i * 16 + g4 * 4 + r;
                float v = acc[i][j][r];
                float p = __shfl_xor(v, 1, 64);
                float o = v;
                if (doRope) {
                    const int t = rr & (NT_ - 1);
                    float cv = cosb[t * 32 + ii], sv = sinb[t * 32 + ii];
                    o = even ? (v * cv - p * sv) : (p * sv + v * cv);
                }
                C[(size_t)rr * N + cc] = o;
            }
        }
}

// ====== small latent GEMM, batched: C[z] f32[M,1024] = A bf16[M,1024] @ BT[z]^T ====
__global__ __launch_bounds__(256) void gemm_lat(
        const unsigned short* __restrict__ A, const unsigned short* __restrict__ BT0,
        int btStride, float* __restrict__ C0, int cStride, int M)
{
    const int z = blockIdx.y;
    const unsigned short* BT = BT0 + (size_t)z * btStride;
    float* C = C0 + (size_t)z * cStride;
    const int n0 = blockIdx.x * 64;
    __shared__ unsigned short As[128 * 64];
    __shared__ unsigned short Bs[64 * 64];
    const int tid = threadIdx.x;
    const int wid = tid >> 6, lane = tid & 63;

    const unsigned short* aSrc[4]; int aWr[4];
    #pragma unroll
    for (int i = 0; i < 4; ++i) {
        int idx = tid + 256 * i;
        int row = idx >> 3, c8 = idx & 7;
        int ar = row; if (ar >= M) ar = M - 1;
        aSrc[i] = A + (size_t)ar * DM_ + c8 * 8;
        aWr[i] = (row * 128 + c8 * 16) ^ ((row & 7) << 4);
    }
    const unsigned short* bSrc[2]; int bWr[2];
    #pragma unroll
    for (int i = 0; i < 2; ++i) {
        int idx = tid + 256 * i;
        int row = idx >> 3, c8 = idx & 7;
        bSrc[i] = BT + (size_t)(n0 + row) * DM_ + c8 * 8;
        bWr[i] = (row * 128 + c8 * 16) ^ ((row & 7) << 4);
    }
    const int wr = wid >> 1, wc = wid & 1;
    int ra[2][4], rb[2][2];
    #pragma unroll
    for (int kk = 0; kk < 2; ++kk) {
        #pragma unroll
        for (int t = 0; t < 4; ++t) {
            int rowa = wr * 64 + t * 16 + (lane & 15);
            int kb = kk * 64 + (lane >> 4) * 16;
            ra[kk][t] = (rowa * 128 + kb) ^ ((rowa & 7) << 4);
        }
        #pragma unroll
        for (int t = 0; t < 2; ++t) {
            int rowb = wc * 32 + t * 16 + (lane & 15);
            int kb = kk * 64 + (lane >> 4) * 16;
            rb[kk][t] = (rowb * 128 + kb) ^ ((rowb & 7) << 4);
        }
    }
    const f32x4 zero = {0.f, 0.f, 0.f, 0.f};
    f32x4 acc[4][2];
    #pragma unroll
    for (int i = 0; i < 4; ++i)
        #pragma unroll
        for (int j = 0; j < 2; ++j) acc[i][j] = zero;

    short8 sa[4], sb[2];
    #pragma unroll
    for (int i = 0; i < 4; ++i) sa[i] = *(const short8*)(aSrc[i]);
    #pragma unroll
    for (int i = 0; i < 2; ++i) sb[i] = *(const short8*)(bSrc[i]);
    const int nk = DM_ >> 6;
    for (int kt = 0; kt < nk; ++kt) {
        #pragma unroll
        for (int i = 0; i < 4; ++i) *(short8*)((char*)As + aWr[i]) = sa[i];
        #pragma unroll
        for (int i = 0; i < 2; ++i) *(short8*)((char*)Bs + bWr[i]) = sb[i];
        __syncthreads();
        if (kt + 1 < nk) {
            int ko = (kt + 1) << 6;
            #pragma unroll
            for (int i = 0; i < 4; ++i) sa[i] = *(const short8*)(aSrc[i] + ko);
            #pragma unroll
            for (int i = 0; i < 2; ++i) sb[i] = *(const short8*)(bSrc[i] + ko);
        }
        #pragma unroll
        for (int kk = 0; kk < 2; ++kk) {
            short8 af[4], bf2[2];
            #pragma unroll
            for (int t = 0; t < 4; ++t) af[t] = *(const short8*)((const char*)As + ra[kk][t]);
            #pragma unroll
            for (int t = 0; t < 2; ++t) bf2[t] = *(const short8*)((const char*)Bs + rb[kk][t]);
            #pragma unroll
            for (int i = 0; i < 4; ++i)
                #pragma unroll
                for (int j = 0; j < 2; ++j)
                    acc[i][j] = __builtin_amdgcn_mfma_f32_16x16x32_bf16(af[i], bf2[j], acc[i][j], 0, 0, 0);
        }
        __syncthreads();
    }
    const int cl = lane & 15, g4 = lane >> 4;
    #pragma unroll
    for (int i = 0; i < 4; ++i)
        #pragma unroll
        for (int j = 0; j < 2; ++j)
            #pragma unroll
            for (int r = 0; r < 4; ++r) {
                int rl = wr * 64 + i * 16 + g4 * 4 + r;
                if (rl < M)
                    C[(size_t)rl * DM_ + n0 + wc * 32 + j * 16 + cl] = acc[i][j][r];
            }
}

// ---------------- attention scores (attn1 only) -------------------------------------
__global__ __launch_bounds__(256) void attn_scores(float* __restrict__ S,
        const float* __restrict__ Q, const float* __restrict__ Km,
        int M, int T, int q_bs, int k_bs, float scale)
{
    const int bh = blockIdx.z, b = bh >> 4, h = bh & 15;
    const int t0 = blockIdx.x * 64, q0 = blockIdx.y * 64;
    __shared__ float Qs[64][65], Ks[64][65];
    const int tid = threadIdx.x;
    const int lr = tid >> 2, lc = (tid & 3) * 16;
    {
        int q = q0 + lr;
        if (q < M) {
            const float* Qp = Q + ((size_t)q_bs * b + q) * DM_ + h * 64 + lc;
            #pragma unroll
            for (int j = 0; j < 16; ++j) Qs[lr][lc + j] = Qp[j];
        } else {
            #pragma unroll
            for (int j = 0; j < 16; ++j) Qs[lr][lc + j] = 0.f;
        }
        const float* Kp = Km + ((size_t)k_bs * b + t0 + lr) * DM_ + h * 64 + lc;
        #pragma unroll
        for (int j = 0; j < 16; ++j) Ks[lr][lc + j] = Kp[j];
    }
    __syncthreads();
    const int ty = tid >> 4, tx = tid & 15;
    float acc[4][4] = {};
    for (int d = 0; d < 64; ++d) {
        float a[4], kk[4];
        #pragma unroll
        for (int i = 0; i < 4; ++i) a[i] = Qs[ty * 4 + i][d];
        #pragma unroll
        for (int j = 0; j < 4; ++j) kk[j] = Ks[tx * 4 + j][d];
        #pragma unroll
        for (int i = 0; i < 4; ++i)
            #pragma unroll
            for (int j = 0; j < 4; ++j) acc[i][j] += a[i] * kk[j];
    }
    #pragma unroll
    for (int i = 0; i < 4; ++i) {
        int q = q0 + ty * 4 + i;
        if (q < M) {
            float* Sp = S + ((size_t)bh * M + q) * T + t0 + tx * 4;
            #pragma unroll
            for (int j = 0; j < 4; ++j) Sp[j] = acc[i][j] * scale;
        }
    }
}

// ---------------- row softmax (attn1, L=2048, register-resident) --------------------
__global__ __launch_bounds__(256) void softmax_rows2048(float* __restrict__ S)
{
    float* p = S + (size_t)blockIdx.x * 2048;
    const int tid = threadIdx.x;
    __shared__ float red[256];
    float v[8];
    float m = -1e30f;
    #pragma unroll
    for (int i = 0; i < 8; ++i) { v[i] = p[tid + i * 256]; m = fmaxf(m, v[i]); }
    red[tid] = m; __syncthreads();
    for (int s = 128; s; s >>= 1) { if (tid < s) red[tid] = fmaxf(red[tid], red[tid + s]); __syncthreads(); }
    m = red[0]; __syncthreads();
    float sum = 0.f;
    #pragma unroll
    for (int i = 0; i < 8; ++i) { v[i] = __expf(v[i] - m); sum += v[i]; }
    red[tid] = sum; __syncthreads();
    for (int s = 128; s; s >>= 1) { if (tid < s) red[tid] += red[tid + s]; __syncthreads(); }
    float inv = 1.f / red[0];
    #pragma unroll
    for (int i = 0; i < 8; ++i) p[tid + i * 256] = v[i] * inv;
}

// ====== fused attention for T=64 (attn2/attn3): QK^T -> softmax -> PV -> bf16 ======
__global__ __launch_bounds__(256) void fused_attn64(unsigned short* __restrict__ Ob,
        const float* __restrict__ Q, const float* __restrict__ Kp,
        const float* __restrict__ Vp, int q_bs)
{
    const int bh = blockIdx.y, b = bh >> 4, h = bh & 15;
    const int q0 = blockIdx.x * 64;
    __shared__ float Qs[64][65], Ks[64][65], Vs[64][65];
    __shared__ float ls[64];
    const int tid = threadIdx.x;
    const int lr = tid >> 2, lc = (tid & 3) * 16;
    {
        const float* Qr = Q + ((size_t)q_bs * b + q0 + lr) * DM_ + h * 64 + lc;
        #pragma unroll
        for (int j = 0; j < 16; ++j) Qs[lr][lc + j] = Qr[j];
        const float* Kr = Kp + ((size_t)64 * b + lr) * DM_ + h * 64 + lc;
        #pragma unroll
        for (int j = 0; j < 16; ++j) Ks[lr][lc + j] = Kr[j];
        const float* Vr = Vp + ((size_t)64 * b + lr) * DM_ + h * 64 + lc;
        #pragma unroll
        for (int j = 0; j < 16; ++j) Vs[lr][lc + j] = Vr[j];
    }
    __syncthreads();
    const int ty = tid >> 4, tx = tid & 15;
    float acc[4][4] = {};
    for (int d = 0; d < 64; ++d) {
        float a[4], kk[4];
        #pragma unroll
        for (int i = 0; i < 4; ++i) a[i] = Qs[ty * 4 + i][d];
        #pragma unroll
        for (int j = 0; j < 4; ++j) kk[j] = Ks[tx * 4 + j][d];
        #pragma unroll
        for (int i = 0; i < 4; ++i)
            #pragma unroll
            for (int j = 0; j < 4; ++j) acc[i][j] += a[i] * kk[j];
    }
    float p[4][4]; float lsum[4];
    #pragma unroll
    for (int i = 0; i < 4; ++i) {
        float m = fmaxf(fmaxf(acc[i][0], acc[i][1]), fmaxf(acc[i][2], acc[i][3]));
        #pragma unroll
        for (int o = 1; o <= 8; o <<= 1) m = fmaxf(m, __shfl_xor(m, o, 64));
        float s = 0.f;
        #pragma unroll
        for (int j = 0; j < 4; ++j) { p[i][j] = __expf(acc[i][j] * 0.125f - m * 0.125f); s += p[i][j]; }
        #pragma unroll
        for (int o = 1; o <= 8; o <<= 1) s += __shfl_xor(s, o, 64);
        lsum[i] = s;
    }
    __syncthreads();
    #pragma unroll
    for (int i = 0; i < 4; ++i) {
        #pragma unroll
        for (int j = 0; j < 4; ++j) Qs[ty * 4 + i][tx * 4 + j] = p[i][j];
        if (tx == 0) ls[ty * 4 + i] = lsum[i];
    }
    __syncthreads();
    float O[4][4] = {};
    for (int t = 0; t < 64; ++t) {
        float pp[4], vv[4];
        #pragma unroll
        for (int i = 0; i < 4; ++i) pp[i] = Qs[ty * 4 + i][t];
        #pragma unroll
        for (int j = 0; j < 4; ++j) vv[j] = Vs[t][tx * 4 + j];
        #pragma unroll
        for (int i = 0; i < 4; ++i)
            #pragma unroll
            for (int j = 0; j < 4; ++j) O[i][j] += pp[i] * vv[j];
    }
    #pragma unroll
    for (int i = 0; i < 4; ++i) {
        float inv = 1.f / ls[ty * 4 + i];
        size_t ofs = ((size_t)q_bs * b + q0 + ty * 4 + i) * DM_ + h * 64 + tx * 4;
        #pragma unroll
        for (int j = 0; j < 4; ++j) Ob[ofs + j] = f2bf(O[i][j] * inv);
    }
}

// ---------------- attn1 PV split over T: partial[bh][c][64q][64d] -------------------
__global__ __launch_bounds__(256) void pv_split(float* __restrict__ part,
        const float* __restrict__ P, const float* __restrict__ V)
{
    const int c = blockIdx.x, bh = blockIdx.y, b = bh >> 4, h = bh & 15;
    __shared__ float Ps[64][65], Vs[64][65];
    const int tid = threadIdx.x;
    const int lr = tid >> 2, lc = (tid & 3) * 16;
    const int ty = tid >> 4, tx = tid & 15;
    float acc[4][4] = {};
    for (int it = 0; it < 4; ++it) {
        const int t0 = c * 256 + it * 64;
        const float* Pp = P + ((size_t)bh * 64 + lr) * NT_ + t0 + lc;
        #pragma unroll
        for (int j = 0; j < 16; ++j) Ps[lr][lc + j] = Pp[j];
        const float* Vp = V + ((size_t)NT_ * b + t0 + lr) * DM_ + h * 64 + lc;
        #pragma unroll
        for (int j = 0; j < 16; ++j) Vs[lr][lc + j] = Vp[j];
        __syncthreads();
        for (int t = 0; t < 64; ++t) {
            float pp[4], vv[4];
            #pragma unroll
            for (int i = 0; i < 4; ++i) pp[i] = Ps[ty * 4 + i][t];
            #pragma unroll
            for (int j = 0; j < 4; ++j) vv[j] = Vs[t][tx * 4 + j];
            #pragma unroll
            for (int i = 0; i < 4; ++i)
                #pragma unroll
                for (int j = 0; j < 4; ++j) acc[i][j] += pp[i] * vv[j];
        }
        __syncthreads();
    }
    float* op = part + ((size_t)bh * 8 + c) * 4096;
    #pragma unroll
    for (int i = 0; i < 4; ++i)
        #pragma unroll
        for (int j = 0; j < 4; ++j)
            op[(ty * 4 + i) * 64 + tx * 4 + j] = acc[i][j];
}

// grid (32 bh, 8 seg): each block sums 512 elems over the 8 chunks
__global__ __launch_bounds__(256) void pv_combine(const float* __restrict__ part,
        unsigned short* __restrict__ Zb)
{
    const int bh = blockIdx.x, b = bh >> 4, h = bh & 15;
    const int seg = blockIdx.y;
    for (int k = 0; k < 2; ++k) {
        int idx = seg * 512 + k * 256 + threadIdx.x;
        int q = idx >> 6, d = idx & 63;
        float s = 0.f;
        #pragma unroll
        for (int c = 0; c < 8; ++c) s += part[((size_t)bh * 8 + c) * 4096 + idx];
        Zb[(size_t)(b * 64 + q) * DM_ + h * 64 + d] = f2bf(s);
    }
}

// ---------------- LayerNorm + add, fp32 + bf16 outputs ------------------------------
__global__ __launch_bounds__(256) void ln_add_dual(const float* __restrict__ X,
        const float* __restrict__ g, const float* __restrict__ bb,
        const float* __restrict__ add, float* __restrict__ out,
        unsigned short* __restrict__ outb)
{
    const int n = blockIdx.x, tid = threadIdx.x;
    const float* x = X + (size_t)n * DM_;
    __shared__ float red[256];
    float v[4]; float s = 0.f;
    #pragma unroll
    for (int i = 0; i < 4; ++i) { v[i] = x[tid + i * 256]; s += v[i]; }
    red[tid] = s; __syncthreads();
    for (int st = 128; st; st >>= 1) { if (tid < st) red[tid] += red[tid + st]; __syncthreads(); }
    float mean = red[0] * (1.f / 1024.f);
    __syncthreads();
    float vs = 0.f;
    #pragma unroll
    for (int i = 0; i < 4; ++i) { float d = v[i] - mean; vs += d * d; }
    red[tid] = vs; __syncthreads();
    for (int st = 128; st; st >>= 1) { if (tid < st) red[tid] += red[tid + st]; __syncthreads(); }
    float inv = 1.f / (sqrtf(red[0] * (1.f / 1023.f)) + 1e-6f);
    #pragma unroll
    for (int i = 0; i < 4; ++i) {
        int d = tid + i * 256;
        float r = g[d] * (v[i] - mean) * inv + bb[d] + add[(size_t)n * DM_ + d];
        out[(size_t)n * DM_ + d] = r;
        outb[(size_t)n * DM_ + d] = f2bf(r);
    }
}

// ---------------- final LN ----------------------------------------------------------
__global__ __launch_bounds__(256) void ln_final(const float* __restrict__ X,
        const float* __restrict__ g, const float* __restrict__ bb,
        const float* __restrict__ t, const float* __restrict__ lb,
        float* __restrict__ out)
{
    const int n = blockIdx.x, tid = threadIdx.x;
    const float* x = X + (size_t)n * DM_;
    __shared__ float red[256];
    float v[4]; float s = 0.f;
    #pragma unroll
    for (int i = 0; i < 4; ++i) { v[i] = x[tid + i * 256]; s += v[i]; }
    red[tid] = s; __syncthreads();
    for (int st = 128; st; st >>= 1) { if (tid < st) red[tid] += red[tid + st]; __syncthreads(); }
    float mean = red[0] * (1.f / 1024.f);
    __syncthreads();
    float vs = 0.f;
    #pragma unroll
    for (int i = 0; i < 4; ++i) { float d = v[i] - mean; vs += d * d; }
    red[tid] = vs; __syncthreads();
    for (int st = 128; st; st >>= 1) { if (tid < st) red[tid] += red[tid + st]; __syncthreads(); }
    float inv = 1.f / (sqrtf(red[0] * (1.f / 1023.f)) + 1e-6f);
    #pragma unroll
    for (int i = 0; i < 4; ++i) {
        int d = tid + i * 256;
        out[(size_t)n * DM_ + d] = g[d] * (v[i] - mean) * inv + bb[d]
                                 + t[(size_t)n * DM_ + d] + lb[d];
    }
}

// ---------------- router ------------------------------------------------------------
__global__ __launch_bounds__(256) void router_kernel(const float* __restrict__ X1,
        const float* __restrict__ Wr, const float* __restrict__ br,
        int* __restrict__ topi, float* __restrict__ gates, int* __restrict__ counts)
{
    const int n = blockIdx.x, tid = threadIdx.x;
    const int e = tid >> 5, l = tid & 31;
    const float* x = X1 + (size_t)n * DM_;
    float s = 0.f;
    for (int k = l; k < DM_; k += 32) s += x[k] * Wr[k * NEXP_ + e];
    for (int off = 16; off; off >>= 1) s += __shfl_down(s, off, 32);
    __shared__ float lg[NEXP_];
    if (l == 0) lg[e] = s + br[e];
    __syncthreads();
    if (tid == 0) {
        float v1 = -1e30f; int i1 = 0;
        for (int ee = 0; ee < NEXP_; ++ee) if (lg[ee] > v1) { v1 = lg[ee]; i1 = ee; }
        float v2 = -1e30f; int i2 = 0;
        for (int ee = 0; ee < NEXP_; ++ee) if (ee != i1 && lg[ee] > v2) { v2 = lg[ee]; i2 = ee; }
        float e2 = __expf(v2 - v1);
        float inv = 1.f / (1.f + e2);
        topi[n * 2] = i1; topi[n * 2 + 1] = i2;
        gates[n * 2] = inv; gates[n * 2 + 1] = e2 * inv;
        atomicAdd(&counts[i1], 1); atomicAdd(&counts[i2], 1);
    }
}

__global__ void zero_counts(int* __restrict__ counts)
{
    if (threadIdx.x < NEXP_) counts[threadIdx.x] = 0;
}

__global__ void router_offsets(const int* __restrict__ counts, int* __restrict__ offs,
                               int* __restrict__ fill)
{
    if (threadIdx.x == 0) {
        int acc = 0;
        for (int e = 0; e < NEXP_; ++e) { offs[e] = acc; acc += counts[e]; fill[e] = 0; }
    }
}

__global__ __launch_bounds__(256) void router_scatter(const int* __restrict__ topi,
        int* __restrict__ fill, const int* __restrict__ offs,
        int* __restrict__ ptok, int* __restrict__ pidx)
{
    int n = blockIdx.x * 256 + threadIdx.x;
    if (n >= NTOK_) return;
    #pragma unroll
    for (int s2 = 0; s2 < 2; ++s2) {
        int e = topi[n * 2 + s2];
        int r = atomicAdd(&fill[e], 1);
        int p = offs[e] + r;
        ptok[p] = n;
        pidx[n * 2 + s2] = p;
    }
}

// ============== MoE up (dual GEMM + silu-glu), 128x64 tile, reg prefetch ===========
__global__ __launch_bounds__(256) void moe_up_mfma(
        const unsigned short* __restrict__ X1b,
        const unsigned short* __restrict__ WTa, const unsigned short* __restrict__ VTa,
        unsigned short* __restrict__ H,
        const int* __restrict__ cnt, const int* __restrict__ offs,
        const int* __restrict__ ptok)
{
    const int e = blockIdx.z;
    const int ce = cnt[e];
    const int m0 = blockIdx.y * 128;
    if (m0 >= ce) return;
    const int n0 = blockIdx.x * 64;
    const int base = offs[e];
    const unsigned short* WT = WTa + (size_t)e * DHID_ * DM_;
    const unsigned short* VT = VTa + (size_t)e * DHID_ * DM_;
    __shared__ unsigned short As[128 * 64];
    __shared__ unsigned short Ws[64 * 64];
    __shared__ unsigned short Vs[64 * 64];
    __shared__ int rtok[128];
    const int tid = threadIdx.x;
    const int wid = tid >> 6, lane = tid & 63;
    if (tid < 128) {
        int r = m0 + tid;
        rtok[tid] = (r < ce) ? ptok[base + r] : ptok[base + ce - 1];
    }
    __syncthreads();

    const unsigned short* aSrc[4]; int aWr[4];
    #pragma unroll
    for (int i = 0; i < 4; ++i) {
        int idx = tid + 256 * i;
        int row = idx >> 3, c8 = idx & 7;
        aSrc[i] = X1b + (size_t)rtok[row] * DM_ + c8 * 8;
        aWr[i] = (row * 128 + c8 * 16) ^ ((row & 7) << 4);
    }
    const unsigned short* wSrc[2]; const unsigned short* vSrc[2]; int bWr[2];
    #pragma unroll
    for (int i = 0; i < 2; ++i) {
        int idx = tid + 256 * i;
        int row = idx >> 3, c8 = idx & 7;
        wSrc[i] = WT + (size_t)(n0 + row) * DM_ + c8 * 8;
        vSrc[i] = VT + (size_t)(n0 + row) * DM_ + c8 * 8;
        bWr[i] = (row * 128 + c8 * 16) ^ ((row & 7) << 4);
    }
    const int wr = wid >> 1, wc = wid & 1;
    int ra[2][4], rb[2][2];
    #pragma unroll
    for (int kk = 0; kk < 2; ++kk) {
        #pragma unroll
        for (int t = 0; t < 4; ++t) {
            int rowa = wr * 64 + t * 16 + (lane & 15);
            int kb = kk * 64 + (lane >> 4) * 16;
            ra[kk][t] = (rowa * 128 + kb) ^ ((rowa & 7) << 4);
        }
        #pragma unroll
        for (int t = 0; t < 2; ++t) {
            int rowb = wc * 32 + t * 16 + (lane & 15);
            int kb = kk * 64 + (lane >> 4) * 16;
            rb[kk][t] = (rowb * 128 + kb) ^ ((rowb & 7) << 4);
        }
    }
    const f32x4 zero = {0.f, 0.f, 0.f, 0.f};
    f32x4 accw[4][2], accv[4][2];
    #pragma unroll
    for (int i = 0; i < 4; ++i)
        #pragma unroll
        for (int j = 0; j < 2; ++j) { accw[i][j] = zero; accv[i][j] = zero; }

    short8 sa[4], sw[2], sv[2];
    #pragma unroll
    for (int i = 0; i < 4; ++i) sa[i] = *(const short8*)(aSrc[i]);
    #pragma unroll
    for (int i = 0; i < 2; ++i) { sw[i] = *(const short8*)(wSrc[i]); sv[i] = *(const short8*)(vSrc[i]); }
    const int nk = DM_ >> 6;
    for (int kt = 0; kt < nk; ++kt) {
        #pragma unroll
        for (int i = 0; i < 4; ++i) *(short8*)((char*)As + aWr[i]) = sa[i];
        #pragma unroll
        for (int i = 0; i < 2; ++i) {
            *(short8*)((char*)Ws + bWr[i]) = sw[i];
            *(short8*)((char*)Vs + bWr[i]) = sv[i];
        }
        __syncthreads();
        if (kt + 1 < nk) {
            int ko = (kt + 1) << 6;
            #pragma unroll
            for (int i = 0; i < 4; ++i) sa[i] = *(const short8*)(aSrc[i] + ko);
            #pragma unroll
            for (int i = 0; i < 2; ++i) { sw[i] = *(const short8*)(wSrc[i] + ko); sv[i] = *(const short8*)(vSrc[i] + ko); }
        }
        #pragma unroll
        for (int kk = 0; kk < 2; ++kk) {
            short8 af[4], bw[2], bv[2];
            #pragma unroll
            for (int t = 0; t < 4; ++t) af[t] = *(const short8*)((const char*)As + ra[kk][t]);
            #pragma unroll
            for (int t = 0; t < 2; ++t) {
                bw[t] = *(const short8*)((const char*)Ws + rb[kk][t]);
                bv[t] = *(const short8*)((const char*)Vs + rb[kk][t]);
            }
            #pragma unroll
            for (int i = 0; i < 4; ++i)
                #pragma unroll
                for (int j = 0; j < 2; ++j) {
                    accw[i][j] = __builtin_amdgcn_mfma_f32_16x16x32_bf16(af[i], bw[j], accw[i][j], 0, 0, 0);
                    accv[i][j] = __builtin_amdgcn_mfma_f32_16x16x32_bf16(af[i], bv[j], accv[i][j], 0, 0, 0);
                }
        }
        __syncthreads();
    }
    const int cl = lane & 15, g4 = lane >> 4;
    #pragma unroll
    for (int i = 0; i < 4; ++i)
        #pragma unroll
        for (int j = 0; j < 2; ++j)
            #pragma unroll
            for (int r = 0; r < 4; ++r) {
                int rl = m0 + wr * 64 + i * 16 + g4 * 4 + r;
                if (rl < ce) {
                    float a = accw[i][j][r], b = accv[i][j][r];
                    float h = a * (b / (1.f + __expf(-b)));
                    H[(size_t)(base + rl) * DHID_ + n0 + wc * 32 + j * 16 + cl] = f2bf(h);
                }
            }
}

// ============== MoE down: PY bf16 = H bf16 @ WoT^T, 128x128, prefetch ==============
__global__ __launch_bounds__(256) void moe_down_mfma(
        const unsigned short* __restrict__ H, const unsigned short* __restrict__ WoTa,
        unsigned short* __restrict__ PY,
        const int* __restrict__ cnt, const int* __restrict__ offs)
{
    const int e = blockIdx.z;
    const int ce = cnt[e];
    const int m0 = blockIdx.y * 128;
    if (m0 >= ce) return;
    const int n0 = blockIdx.x * 128;
    const int base = offs[e];
    const unsigned short* WoT = WoTa + (size_t)e * DM_ * DHID_;
    __shared__ unsigned short As[128 * 64];
    __shared__ unsigned short Bs[128 * 64];
    const int tid = threadIdx.x;
    const int wid = tid >> 6, lane = tid & 63;

    const unsigned short* aSrc[4]; const unsigned short* bSrc[4]; int sWr[4];
    #pragma unroll
    for (int i = 0; i < 4; ++i) {
        int idx = tid + 256 * i;
        int row = idx >> 3, c8 = idx & 7;
        int r = m0 + row; if (r >= ce) r = ce - 1;
        aSrc[i] = H + (size_t)(base + r) * DHID_ + c8 * 8;
        bSrc[i] = WoT + (size_t)(n0 + row) * DHID_ + c8 * 8;
        sWr[i] = (row * 128 + c8 * 16) ^ ((row & 7) << 4);
    }
    const int wr = wid >> 1, wc = wid & 1;
    int ra[2][4], rb[2][4];
    #pragma unroll
    for (int kk = 0; kk < 2; ++kk) {
        #pragma unroll
        for (int t = 0; t < 4; ++t) {
            int kb = kk * 64 + (lane >> 4) * 16;
            int rowa = wr * 64 + t * 16 + (lane & 15);
            ra[kk][t] = (rowa * 128 + kb) ^ ((rowa & 7) << 4);
            int rowb = wc * 64 + t * 16 + (lane & 15);
            rb[kk][t] = (rowb * 128 + kb) ^ ((rowb & 7) << 4);
        }
    }
    const f32x4 zero = {0.f, 0.f, 0.f, 0.f};
    f32x4 acc[4][4];
    #pragma unroll
    for (int i = 0; i < 4; ++i)
        #pragma unroll
        for (int j = 0; j < 4; ++j) acc[i][j] = zero;

    short8 sa[4], sb[4];
    #pragma unroll
    for (int i = 0; i < 4; ++i) { sa[i] = *(const short8*)(aSrc[i]); sb[i] = *(const short8*)(bSrc[i]); }
    const int nk = DHID_ >> 6;
    for (int kt = 0; kt < nk; ++kt) {
        #pragma unroll
        for (int i = 0; i < 4; ++i) {
            *(short8*)((char*)As + sWr[i]) = sa[i];
            *(short8*)((char*)Bs + sWr[i]) = sb[i];
        }
        __syncthreads();
        if (kt + 1 < nk) {
            int ko = (kt + 1) << 6;
            #pragma unroll
            for (int i = 0; i < 4; ++i) { sa[i] = *(const short8*)(aSrc[i] + ko); sb[i] = *(const short8*)(bSrc[i] + ko); }
        }
        #pragma unroll
        for (int kk = 0; kk < 2; ++kk) {
            short8 af[4], bfr[4];
            #pragma unroll
            for (int t = 0; t < 4; ++t) {
                af[t]  = *(const short8*)((const char*)As + ra[kk][t]);
                bfr[t] = *(const short8*)((const char*)Bs + rb[kk][t]);
            }
            #pragma unroll
            for (int i = 0; i < 4; ++i)
                #pragma unroll
                for (int j = 0; j < 4; ++j)
                    acc[i][j] = __builtin_amdgcn_mfma_f32_16x16x32_bf16(af[i], bfr[j], acc[i][j], 0, 0, 0);
        }
        __syncthreads();
    }
    const int cl = lane & 15, g4 = lane >> 4;
    #pragma unroll
    for (int i = 0; i < 4; ++i)
        #pragma unroll
        for (int j = 0; j < 4; ++j)
            #pragma unroll
            for (int r = 0; r < 4; ++r) {
                int rl = m0 + wr * 64 + i * 16 + g4 * 4 + r;
                if (rl < ce)
                    PY[(size_t)(base + rl) * DM_ + n0 + wc * 64 + j * 16 + cl] = f2bf(acc[i][j][r]);
            }
}

// ---------------- combine (PY bf16) --------------------------------------------------
__global__ __launch_bounds__(256) void moe_combine(const unsigned short* __restrict__ PY,
        const int* __restrict__ pidx, const float* __restrict__ gates,
        float* __restrict__ MO)
{
    int n = blockIdx.x, tid = threadIdx.x;
    int p0 = pidx[n * 2], p1 = pidx[n * 2 + 1];
    float g0 = gates[n * 2], g1 = gates[n * 2 + 1];
    #pragma unroll
    for (int i = 0; i < 4; ++i) {
        int d = tid + i * 256;
        MO[(size_t)n * DM_ + d] = g0 * bf2f(PY[(size_t)p0 * DM_ + d])
                                + g1 * bf2f(PY[(size_t)p1 * DM_ + d]);
    }
}

extern "C" void kernel_launch(void* const* d_in, const int* in_sizes, int n_in,
                              void* d_out, int out_size, void* d_ws, size_t ws_size,
                              hipStream_t stream)
{
    const float* x      = (const float*)d_in[0];
    const float* cosb   = (const float*)d_in[1];
    const float* sinb   = (const float*)d_in[2];
    const float* ln1g   = (const float*)d_in[3];
    const float* ln1b   = (const float*)d_in[4];
    const float* ln2g   = (const float*)d_in[5];
    const float* ln2b   = (const float*)d_in[6];
    const float* ln3g   = (const float*)d_in[7];
    const float* ln3b   = (const float*)d_in[8];
    const float* Lat    = (const float*)d_in[9];
    const float* Wq_lat = (const float*)d_in[10];
    const float* Wk_in  = (const float*)d_in[11];
    const float* Wv_in  = (const float*)d_in[12];
    const float* Wq_in  = (const float*)d_in[13];
    const float* Wk_lat = (const float*)d_in[14];
    const float* Wv_lat = (const float*)d_in[15];
    const float* Wout   = (const float*)d_in[16];
    const float* rW     = (const float*)d_in[17];
    const float* rb     = (const float*)d_in[18];
    const float* eW     = (const float*)d_in[19];
    const float* eV     = (const float*)d_in[20];
    const float* eWo    = (const float*)d_in[21];
    const float* linW   = (const float*)d_in[22];
    const float* linb   = (const float*)d_in[23];
    float* out = (float*)d_out;

    float* ws = (float*)d_ws;
    const size_t M1 = 1024 * 1024;
    float* buf0 = ws;                 // K-proj / MoE out
    float* buf1 = ws + 4 * M1;        // V-proj / attn out / X2
    float* buf2 = ws + 8 * M1;        // Q-proj(rope) / X1
    float* buf3 = ws + 12 * M1;       // S1 / final-linear out
    size_t off = 16 * M1;
    float* qlat = ws + off; off += 65536;
    float* qlb  = ws + off; off += 131072;
    float* klb  = ws + off; off += 131072;
    float* vlb  = ws + off; off += 131072;
    float* s2b  = ws + off; off += 131072;
    float* z2b  = ws + off; off += 131072;
    float* kzb  = ws + off; off += 131072;
    float* vzb  = ws + off; off += 131072;
    float* gates = ws + off; off += 8192;
    int* iarea = (int*)(ws + off); off += 32768;
    int* topi   = iarea;
    int* counts = iarea + 8192;
    int* offs   = iarea + 8200;
    int* fill   = iarea + 8208;
    int* ptok   = iarea + 8216;
    int* pidx   = iarea + 16408;
    unsigned short* zb_b  = (unsigned short*)(ws + off); off += 65536;
    unsigned short* z2b_b = (unsigned short*)(ws + off); off += 65536;
    unsigned short* latb  = (unsigned short*)(ws + off); off += 32768;
    unsigned short* x1b   = (unsigned short*)(ws + off); off += 2 * M1;
    unsigned short* WkT   = (unsigned short*)(ws + off); off += 3 * (M1 / 2);
    unsigned short* WoutT = (unsigned short*)(ws + off); off += M1 / 2;   // + linWT contiguous
    unsigned short* linWT = (unsigned short*)(ws + off); off += M1 / 2;
    unsigned short* WlatT = (unsigned short*)(ws + off); off += 3 * (M1 / 2);

    unsigned short* Hbuf  = (unsigned short*)(ws + 24 * M1);
    unsigned short* actb  = (unsigned short*)(ws + 24 * M1);   // alias
    unsigned short* x2b   = (unsigned short*)(ws + 24 * M1);   // alias
    float* pvpart         = ws + 26 * M1;
    unsigned short* eWT   = (unsigned short*)(ws + 40 * M1);   // eWT..eVT contiguous
    unsigned short* eVT   = (unsigned short*)(ws + 56 * M1);
    unsigned short* eWoT  = eWT;
    unsigned short* PY    = (unsigned short*)(ws + 56 * M1);   // bf16, aliases eVT

    dim3 blk(256);

    zero_counts<<<1, 64, 0, stream>>>(counts);

    // weight prep
    tconv3<<<dim3(16, 16, 3), blk, 0, stream>>>(Wk_in, Wv_in, Wq_in, WkT);
    tconv3<<<dim3(16, 16, 2), blk, 0, stream>>>(Wout, linW, linW, WoutT);   // z=0,1 only
    tconv3<<<dim3(16, 16, 3), blk, 0, stream>>>(Wq_lat, Wk_lat, Wv_lat, WlatT);
    tconvEV<<<dim3(64, 16, 16), blk, 0, stream>>>(eW, eV, eWT);
    c2b<<<2048, blk, 0, stream>>>(x, actb, 524288);
    c2b<<<32, blk, 0, stream>>>(Lat, latb, 8192);

    // qlat = Lat @ Wq_lat
    gemm_lat<<<dim3(16, 1), blk, 0, stream>>>(latb, WlatT, (int)M1, qlat, 0, 64);

    // projections (K rope z=0, V plain z=1, Q rope z=2)
    gemm_proj3<<<dim3(8, 32, 3), blk, 0, stream>>>(actb, WkT, buf0, cosb, sinb);

    // attn1: latents query tokens
    attn_scores<<<dim3(32, 1, 32), blk, 0, stream>>>(buf3, qlat, buf0, 64, 2048, 0, 2048, 0.125f);
    softmax_rows2048<<<2048, blk, 0, stream>>>(buf3);
    pv_split<<<dim3(8, 32), blk, 0, stream>>>(pvpart, buf3, buf1);
    pv_combine<<<dim3(32, 8), blk, 0, stream>>>(pvpart, zb_b);

    // attn2: latents self-attention (fused)
    gemm_lat<<<dim3(16, 3), blk, 0, stream>>>(zb_b, WlatT, (int)M1, qlb, 131072, 128);
    fused_attn64<<<dim3(1, 32), blk, 0, stream>>>(z2b_b, qlb, klb, vlb, 64);

    // attn3: tokens query latents (fused)
    gemm_lat<<<dim3(16, 2), blk, 0, stream>>>(z2b_b, WlatT + M1, (int)M1, kzb, 131072, 128);
    fused_attn64<<<dim3(32, 32), blk, 0, stream>>>(actb, buf2, kzb, vzb, 2048);
    gemm_bf16_128<<<dim3(8, 32), blk, 0, stream>>>(actb, WoutT, buf1, 4096, 1024, 1024);

    // residual 1: X1 = LN1(x) + attn
    ln_add_dual<<<4096, blk, 0, stream>>>(x, ln1g, ln1b, buf1, buf2, x1b);

    // MoE
    router_kernel<<<4096, blk, 0, stream>>>(buf2, rW, rb, topi, gates, counts);
    router_offsets<<<1, 64, 0, stream>>>(counts, offs, fill);
    router_scatter<<<16, blk, 0, stream>>>(topi, fill, offs, ptok, pidx);
    moe_up_mfma<<<dim3(64, 32, 8), blk, 0, stream>>>(x1b, eWT, eVT, Hbuf, counts, offs, ptok);
    tconv<<<dim3(16, 64, 8), blk, 0, stream>>>(eWo, eWoT, 4096, 1024);
    moe_down_mfma<<<dim3(8, 32, 8), blk, 0, stream>>>(Hbuf, eWoT, PY, counts, offs);
    moe_combine<<<4096, blk, 0, stream>>>(PY, pidx, gates, buf0);

    // residual 2: X2 = LN2(X1) + MoE
    ln_add_dual<<<4096, blk, 0, stream>>>(buf2, ln2g, ln2b, buf0, buf1, x2b);

    // final linear + residual 3
    gemm_bf16_128<<<dim3(8, 32), blk, 0, stream>>>(x2b, linWT, buf3, 4096, 1024, 1024);
    ln_final<<<4096, blk, 0, stream>>>(buf1, ln3g, ln3b, buf3, linb, out);
}